// Round 1
// baseline (1031.718 us; speedup 1.0000x reference)
//
#include <hip/hip_runtime.h>

#define S_ 1024
#define M_ 1024
#define T_ 2048
#define B_ 4
#define H_ 16
#define DM_ 1024
#define DH_ 64

typedef __attribute__((ext_vector_type(8))) short s16x8;
typedef __attribute__((ext_vector_type(16))) float f32x16;

__device__ __forceinline__ unsigned short f2b(float x){
  unsigned int u = __float_as_uint(x);
  u = (u + 0x7fffu + ((u>>16)&1u)) >> 16;
  return (unsigned short)u;
}
__device__ __forceinline__ float b2f(unsigned short h){
  return __uint_as_float(((unsigned int)h)<<16);
}
__device__ __forceinline__ uint4 pack8(const float* v){
  uint4 o;
  o.x = (unsigned)f2b(v[0]) | ((unsigned)f2b(v[1])<<16);
  o.y = (unsigned)f2b(v[2]) | ((unsigned)f2b(v[3])<<16);
  o.z = (unsigned)f2b(v[4]) | ((unsigned)f2b(v[5])<<16);
  o.w = (unsigned)f2b(v[6]) | ((unsigned)f2b(v[7])<<16);
  return o;
}
__device__ __forceinline__ void glds16(const unsigned short* g, unsigned short* l){
  __builtin_amdgcn_global_load_lds((const __attribute__((address_space(1))) void*)g,
                                   (__attribute__((address_space(3))) void*)l, 16, 0, 0);
}

// ---------------- cast kernels ----------------
__global__ __launch_bounds__(256) void cast_cat(const float* __restrict__ a,
    const float* __restrict__ b, unsigned short* __restrict__ dst, int n8, int na8)
{
  int i = blockIdx.x*256 + threadIdx.x;
  if (i >= n8) return;
  const float* src = (i < na8) ? (a + (size_t)i*8) : (b + ((size_t)(i-na8))*8);
  float4 x0 = *(const float4*)src;
  float4 x1 = *(const float4*)(src+4);
  float f[8] = {x0.x,x0.y,x0.z,x0.w,x1.x,x1.y,x1.z,x1.w};
  *(uint4*)&dst[(size_t)i*8] = pack8(f);
}

// ---------------- GEMM: C[M][N] = A[M][K] @ B[N][K]^T  (bf16 in, NT) ----------------
__global__ __launch_bounds__(256) void gemm_nt(const unsigned short* __restrict__ A,
    const unsigned short* __restrict__ Bw, void* __restrict__ Cout,
    const float* __restrict__ res, int Ntot, int K, int mode)
{
  __shared__ __align__(16) unsigned short a_s[128*64];
  __shared__ __align__(16) unsigned short b_s[128*64];
  const int tid = threadIdx.x;
  const int lane = tid & 63, wave = tid >> 6;
  const int wr = wave >> 1, wc = wave & 1;
  const long m0 = (long)blockIdx.y * 128, n0 = (long)blockIdx.x * 128;
  f32x16 acc[2][2];
  for (int qa=0;qa<2;qa++) for(int qb=0;qb<2;qb++) for (int e=0;e<16;e++) acc[qa][qb][e]=0.f;
  int srow[4], scol[4];
  for (int c = 0; c < 4; c++) {
    int ch = c*256 + tid;
    srow[c] = ch >> 3;
    scol[c] = (((ch & 7) ^ (srow[c] & 7))) * 8;
  }
  for (int k0 = 0; k0 < K; k0 += 64) {
    for (int c = 0; c < 4; c++) {
      int ch = c*256 + tid;
      glds16(&A[(size_t)(m0+srow[c])*K + k0 + scol[c]], &a_s[ch*8]);
      glds16(&Bw[(size_t)(n0+srow[c])*K + k0 + scol[c]], &b_s[ch*8]);
    }
    __syncthreads();
    for (int ks = 0; ks < 4; ks++) {
      const int kb = ks*2 + (lane>>5);
      s16x8 af[2], bf[2];
      for (int q = 0; q < 2; q++) {
        int ra = wr*64 + q*32 + (lane&31);
        int rb = wc*64 + q*32 + (lane&31);
        af[q] = *(const s16x8*)&a_s[ra*64 + ((kb ^ (ra&7))<<3)];
        bf[q] = *(const s16x8*)&b_s[rb*64 + ((kb ^ (rb&7))<<3)];
      }
      for (int qr=0;qr<2;qr++)
        for (int qc2=0;qc2<2;qc2++)
          acc[qr][qc2] = __builtin_amdgcn_mfma_f32_32x32x16_bf16(af[qr], bf[qc2], acc[qr][qc2], 0,0,0);
    }
    __syncthreads();
  }
  for (int qr=0;qr<2;qr++)
    for (int qc2=0;qc2<2;qc2++)
      for (int e=0;e<16;e++){
        long row = m0 + wr*64 + qr*32 + (e&3) + 8*(e>>2) + 4*(lane>>5);
        long col = n0 + wc*64 + qc2*32 + (lane&31);
        size_t o = (size_t)row*Ntot + col;
        if (mode == 0) ((unsigned short*)Cout)[o] = f2b(acc[qr][qc2][e]);
        else           ((float*)Cout)[o] = acc[qr][qc2][e] + res[o];
      }
}

// ---------------- scatter: q + biases, per-head layout ----------------
__global__ __launch_bounds__(256) void scatter_quv(const unsigned short* __restrict__ qkvo,
   const float* __restrict__ u, const float* __restrict__ v,
   unsigned short* __restrict__ QU, unsigned short* __restrict__ QV)
{
  int gid = blockIdx.x*256 + threadIdx.x;   // B*H*S*8 = 524288
  int d0 = (gid & 7) * 8;
  int i  = (gid >> 3) & (S_-1);
  int bh = gid >> 13;
  int b = bh >> 4, h = bh & 15;
  size_t src = (size_t)((M_+i)*B_ + b)*3072 + h*64 + d0;
  uint4 q8 = *(const uint4*)&qkvo[src];
  float f[8];
  f[0]=b2f(q8.x&0xffff); f[1]=b2f(q8.x>>16); f[2]=b2f(q8.y&0xffff); f[3]=b2f(q8.y>>16);
  f[4]=b2f(q8.z&0xffff); f[5]=b2f(q8.z>>16); f[6]=b2f(q8.w&0xffff); f[7]=b2f(q8.w>>16);
  float fu[8], fv[8];
  for (int e=0;e<8;e++){ fu[e] = f[e] + u[h*64+d0+e]; fv[e] = f[e] + v[h*64+d0+e]; }
  size_t dst = ((size_t)bh*S_ + i)*64 + d0;
  *(uint4*)&QU[dst] = pack8(fu);
  *(uint4*)&QV[dst] = pack8(fv);
}

// ---------------- scatter_vt: VT[bh][d][t] = V[t][b][h][d] (LDS transpose) ----------------
__global__ __launch_bounds__(256) void scatter_vt(const unsigned short* __restrict__ qkvo,
    unsigned short* __restrict__ VT)
{
  __shared__ __align__(16) unsigned short v_s[64*72];
  const int tid = threadIdx.x;
  const int bh = blockIdx.x, b = bh>>4, h = bh&15;
  const int t0 = blockIdx.y*64;
  const unsigned short* Vg = qkvo + (size_t)b*3072 + 2048 + h*64;
  for (int c=0;c<2;c++){
    int ch = c*256 + tid;
    int r = ch>>3, off = (ch&7)*8;
    *(uint4*)&v_s[r*72+off] = *(const uint4*)&Vg[(size_t)(t0+r)*12288 + off];
  }
  __syncthreads();
  for (int c=0;c<2;c++){
    int ch = c*256 + tid;
    int d = ch>>3, toff = (ch&7)*8;
    unsigned short vals[8];
    for (int e=0;e<8;e++) vals[e] = v_s[(toff+e)*72 + d];
    uint4 pk;
    pk.x = (unsigned)vals[0] | ((unsigned)vals[1]<<16);
    pk.y = (unsigned)vals[2] | ((unsigned)vals[3]<<16);
    pk.z = (unsigned)vals[4] | ((unsigned)vals[5]<<16);
    pk.w = (unsigned)vals[6] | ((unsigned)vals[7]<<16);
    *(uint4*)&VT[((size_t)bh*64 + d)*T_ + t0 + toff] = pk;
  }
}

// ---------------- fused attention v5 ----------------
// Changes vs v4:
//   * LDS aliasing: rg_s holds R-window (band GEMM input) then G (band output);
//     kp_s holds K (AC input) then P (softmax probs). 79360B -> 53648B => 3 blocks/CU.
//   * T14 async-STAGE: next j-tile's K/VT/R prefetched into 8 uint4 regs right after
//     the staging barrier; written to LDS at the top of the next iteration.
//   * T5 s_setprio(1) around the MFMA clusters.
__global__ __launch_bounds__(256,3) void flash_attn4(
    const unsigned short* __restrict__ QU, const unsigned short* __restrict__ QV,
    const unsigned short* __restrict__ qkvo, const unsigned short* __restrict__ VT,
    const unsigned short* __restrict__ relo, unsigned short* __restrict__ AV)
{
  __shared__ __align__(16) unsigned short qu_s[64*72];
  __shared__ __align__(16) unsigned short qv_s[65*72];
  __shared__ __align__(16) unsigned short kp_s[64*72];   // K during AC, then P
  __shared__ __align__(16) unsigned short vT_s[64*72];
  __shared__ __align__(16) unsigned short rg_s[64*128];  // R window (XOR slots), then G
  __shared__ float l_s[64];

  const int tid = threadIdx.x, lane = tid&63, wave = tid>>6;
  const int bh = blockIdx.x, b = bh>>4, h = bh&15;
  const int i0 = blockIdx.y*64;
  const int qr = wave>>1, qc = wave&1;
  const unsigned short* QUb = QU + (size_t)bh*S_*DH_;
  const unsigned short* QVb = QV + (size_t)bh*S_*DH_;
  const unsigned short* Kg  = qkvo + (size_t)b*3072 + 1024 + h*64;   // + t*12288
  const unsigned short* VTb = VT + (size_t)bh*64*T_;
  const unsigned short* Rg  = relo + (size_t)b*1024 + h*64;          // + t*4096

  // stage QU rows i0..i0+63 and QV rows i0..i0+64 (65 rows; +64 clamped)
  for (int c=0;c<2;c++){
    int ch = c*256+tid; int row = ch>>3, off=(ch&7)*8;
    *(uint4*)&qu_s[row*72+off] = *(const uint4*)&QUb[(size_t)(i0+row)*64 + off];
    *(uint4*)&qv_s[row*72+off] = *(const uint4*)&QVb[(size_t)(i0+row)*64 + off];
  }
  if (tid < 8) {
    int rr = i0 + 64; if (rr > S_-1) rr = S_-1;
    *(uint4*)&qv_s[64*72 + tid*8] = *(const uint4*)&QVb[(size_t)rr*64 + tid*8];
  }

  f32x16 acc_o;
  for (int e=0;e<16;e++) acc_o[e]=0.f;
  float lreg = 0.f;

  const int col = qc*32 + (lane&31);
  const int rbase = qr*32 + 4*(lane>>5);

  // prefetch registers (named, static — no scratch)
  uint4 pk0, pk1, pv0, pv1, pr0, pr1, pr2, pr3;
  const int r0c = tid>>3,        o0c = (tid&7)*8;
  const int r1c = (256+tid)>>3,  o1c = ((256+tid)&7)*8;

#define PREF(J) do { \
    pk0 = *(const uint4*)&Kg [(size_t)((J)+r0c)*12288 + o0c]; \
    pk1 = *(const uint4*)&Kg [(size_t)((J)+r1c)*12288 + o1c]; \
    pv0 = *(const uint4*)&VTb[(size_t)r0c*T_ + (J) + o0c];    \
    pv1 = *(const uint4*)&VTb[(size_t)r1c*T_ + (J) + o1c];    \
    int jdmax_ = (J)+63-i0, jdmin_ = (J)-63-i0;               \
    int cls_ = (jdmax_<=1024)?0:((jdmin_>=1026)?2:1);         \
    int wb_ = (cls_==2)?((J)-i0-1089):((J)-i0+960);           \
    { int rr_=(0*256+tid)>>3; int t_=wb_+rr_; t_=t_<0?0:(t_>T_-1?T_-1:t_); pr0=*(const uint4*)&Rg[(size_t)t_*4096 + ((0*256+tid)&7)*8]; } \
    { int rr_=(1*256+tid)>>3; int t_=wb_+rr_; t_=t_<0?0:(t_>T_-1?T_-1:t_); pr1=*(const uint4*)&Rg[(size_t)t_*4096 + ((1*256+tid)&7)*8]; } \
    { int rr_=(2*256+tid)>>3; int t_=wb_+rr_; t_=t_<0?0:(t_>T_-1?T_-1:t_); pr2=*(const uint4*)&Rg[(size_t)t_*4096 + ((2*256+tid)&7)*8]; } \
    { int rr_=(3*256+tid)>>3; int t_=wb_+rr_; t_=t_<0?0:(t_>T_-1?T_-1:t_); pr3=*(const uint4*)&Rg[(size_t)t_*4096 + ((3*256+tid)&7)*8]; } \
  } while(0)

#define STORE_STAGE() do { \
    *(uint4*)&kp_s[r0c*72+o0c] = pk0; \
    *(uint4*)&kp_s[r1c*72+o1c] = pk1; \
    *(uint4*)&vT_s[r0c*72+o0c] = pv0; \
    *(uint4*)&vT_s[r1c*72+o1c] = pv1; \
    { int rr_=(0*256+tid)>>3, of_=(0*256+tid)&7; *(uint4*)&rg_s[rr_*64 + ((of_^(rr_&7))<<3)] = pr0; } \
    { int rr_=(1*256+tid)>>3, of_=(1*256+tid)&7; *(uint4*)&rg_s[rr_*64 + ((of_^(rr_&7))<<3)] = pr1; } \
    { int rr_=(2*256+tid)>>3, of_=(2*256+tid)&7; *(uint4*)&rg_s[rr_*64 + ((of_^(rr_&7))<<3)] = pr2; } \
    { int rr_=(3*256+tid)>>3, of_=(3*256+tid)&7; *(uint4*)&rg_s[rr_*64 + ((of_^(rr_&7))<<3)] = pr3; } \
  } while(0)

  PREF(0);

  for (int j0 = 0; j0 < T_; j0 += 64) {
    const int jdmax = j0 + 63 - i0;
    const int jdmin = j0 - 63 - i0;
    const int cls = (jdmax <= 1024) ? 0 : ((jdmin >= 1026) ? 2 : 1);
    const int ashift = (cls == 2) ? 1 : 0;

    STORE_STAGE();             // write prefetched K/VT/R (prev iter's readers done at B5)
    __syncthreads();           // B1: staging (and first-iter qu/qv) visible

    if (j0 + 64 < T_) PREF(j0 + 64);   // issue next tile's loads; consumed next iter

    // band GEMM: 2 quads per wave, results kept in regs until after B2
    f32x16 gacc0, gacc1;
    for (int e=0;e<16;e++){ gacc0[e]=0.f; gacc1[e]=0.f; }
    __builtin_amdgcn_s_setprio(1);
    for (int ks=0; ks<4; ks++){
      int koff = ks*16 + (lane>>5)*8, kb = ks*2 + (lane>>5);
      int ar = qr*32 + (lane&31) + ashift;
      s16x8 a  = *(const s16x8*)&qv_s[ar*72 + koff];
      {
        int br = (qc*2+0)*32 + (lane&31);
        s16x8 bb = *(const s16x8*)&rg_s[br*64 + ((kb ^ (br&7))<<3)];
        gacc0 = __builtin_amdgcn_mfma_f32_32x32x16_bf16(a, bb, gacc0, 0,0,0);
      }
      {
        int br = (qc*2+1)*32 + (lane&31);
        s16x8 bb = *(const s16x8*)&rg_s[br*64 + ((kb ^ (br&7))<<3)];
        gacc1 = __builtin_amdgcn_mfma_f32_32x32x16_bf16(a, bb, gacc1, 0,0,0);
      }
    }
    // AC quad (reads kp_s = K)
    f32x16 acc;
    for (int e=0;e<16;e++) acc[e]=0.f;
    for (int ks=0; ks<4; ks++){
      int koff = ks*16 + (lane>>5)*8;
      s16x8 a  = *(const s16x8*)&qu_s[(qr*32+(lane&31))*72 + koff];
      s16x8 bq = *(const s16x8*)&kp_s[(qc*32+(lane&31))*72 + koff];
      acc = __builtin_amdgcn_mfma_f32_32x32x16_bf16(a, bq, acc, 0,0,0);
    }
    __builtin_amdgcn_s_setprio(0);
    __syncthreads();           // B2: all reads of rg_s(R) and kp_s(K) complete

    // write G into rg_s (aliases dead R window)
    for (int e=0;e<16;e++){
      int r = rbase + (e&3) + 8*(e>>2);
      rg_s[r*128 + (qc*2+0)*32 + (lane&31)] = f2b(gacc0[e]);
      rg_s[r*128 + (qc*2+1)*32 + (lane&31)] = f2b(gacc1[e]);
    }
    __syncthreads();           // B3: G visible

    // assembly phase A (all of cls 0/2; jd<=1025 part of cls 1) -> P into kp_s
    for (int e=0;e<16;e++){
      int r = rbase + (e&3) + 8*(e>>2);
      int jd = j0 + col - (i0 + r);
      if (cls == 1 && jd >= 1026) continue;
      float bd = (jd == 1025) ? 0.f : b2f(rg_s[r*128 + (col - r + 63)]);
      kp_s[r*72 + col] = f2b(__expf((acc[e] + bd) * 0.125f));
    }
    if (cls == 1) {
      __syncthreads();         // C1: G reads done -> can overwrite rg_s
      const int wb2 = j0 - i0 - 1089;
      for (int c=0;c<4;c++){
        int ch = c*256+tid; int rr = ch>>3, off = ch&7;
        int t = wb2 + rr; t = t < 0 ? 0 : (t > T_-1 ? T_-1 : t);
        *(uint4*)&rg_s[rr*64 + ((off ^ (rr&7))<<3)] = *(const uint4*)&Rg[(size_t)t*4096 + off*8];
      }
      __syncthreads();         // C2: wrap R window visible
      f32x16 g2a, g2b;
      for (int e=0;e<16;e++){ g2a[e]=0.f; g2b[e]=0.f; }
      __builtin_amdgcn_s_setprio(1);
      for (int ks=0; ks<4; ks++){
        int koff = ks*16 + (lane>>5)*8, kb = ks*2 + (lane>>5);
        int ar = qr*32 + (lane&31) + 1;    // wrap band uses QV[i+1]
        s16x8 a  = *(const s16x8*)&qv_s[ar*72 + koff];
        {
          int br = (qc*2+0)*32 + (lane&31);
          s16x8 bb = *(const s16x8*)&rg_s[br*64 + ((kb ^ (br&7))<<3)];
          g2a = __builtin_amdgcn_mfma_f32_32x32x16_bf16(a, bb, g2a, 0,0,0);
        }
        {
          int br = (qc*2+1)*32 + (lane&31);
          s16x8 bb = *(const s16x8*)&rg_s[br*64 + ((kb ^ (br&7))<<3)];
          g2b = __builtin_amdgcn_mfma_f32_32x32x16_bf16(a, bb, g2b, 0,0,0);
        }
      }
      __builtin_amdgcn_s_setprio(0);
      __syncthreads();         // C3: wrap R reads done
      for (int e=0;e<16;e++){
        int r = rbase + (e&3) + 8*(e>>2);
        rg_s[r*128 + (qc*2+0)*32 + (lane&31)] = f2b(g2a[e]);
        rg_s[r*128 + (qc*2+1)*32 + (lane&31)] = f2b(g2b[e]);
      }
      __syncthreads();         // C4: G2 visible
      for (int e=0;e<16;e++){
        int r = rbase + (e&3) + 8*(e>>2);
        int jd = j0 + col - (i0 + r);
        if (jd < 1026) continue;
        float bd = b2f(rg_s[r*128 + (col - r + 63)]);
        kp_s[r*72 + col] = f2b(__expf((acc[e] + bd) * 0.125f));
      }
    }
    __syncthreads();           // B4: P visible

    // rowsum (4 threads per row) from kp_s (= P)
    {
      int rr = tid>>2, cb = (tid&3)*16;
      uint4 x0 = *(const uint4*)&kp_s[rr*72+cb];
      uint4 x1 = *(const uint4*)&kp_s[rr*72+cb+8];
      unsigned vs[8] = {x0.x,x0.y,x0.z,x0.w,x1.x,x1.y,x1.z,x1.w};
      float s = 0.f;
      for (int e=0;e<8;e++) s += b2f((unsigned short)(vs[e]&0xffff)) + b2f((unsigned short)(vs[e]>>16));
      s += __shfl_xor(s, 1, 64);
      s += __shfl_xor(s, 2, 64);
      if ((tid&3)==0) lreg += s;
    }
    // PV quad
    __builtin_amdgcn_s_setprio(1);
    for (int ks=0; ks<4; ks++){
      int koff = ks*16 + (lane>>5)*8;
      s16x8 a  = *(const s16x8*)&kp_s[(qr*32+(lane&31))*72 + koff];
      s16x8 bv = *(const s16x8*)&vT_s[(qc*32+(lane&31))*72 + koff];
      acc_o = __builtin_amdgcn_mfma_f32_32x32x16_bf16(a, bv, acc_o, 0,0,0);
    }
    __builtin_amdgcn_s_setprio(0);
    __syncthreads();           // B5: kp_s(P)/vT_s/rg_s reads done -> next STORE safe
  }

  if ((tid&3)==0) l_s[tid>>2] = lreg;
  __syncthreads();
  for (int e=0;e<16;e++){
    int r = rbase + (e&3) + 8*(e>>2);
    float oo = acc_o[e] / l_s[r];
    AV[ ((size_t)(i0+r)*B_ + b)*(H_*DH_) + h*DH_ + col ] = f2b(oo);
  }
#undef PREF
#undef STORE_STAGE
}

// ---------------- LayerNorm ----------------
__global__ __launch_bounds__(256) void ln_kernel(const float* __restrict__ y,
    const float* __restrict__ g, const float* __restrict__ be, float* __restrict__ o)
{
  __shared__ float red[8];
  int row = blockIdx.x, tid = threadIdx.x;
  const float* yr = y + (size_t)row*DM_;
  float v[4];
  for (int e=0;e<4;e++) v[e] = yr[tid + 256*e];
  float s = v[0]+v[1]+v[2]+v[3];
  for (int off=32; off>0; off>>=1) s += __shfl_down(s, off, 64);
  if ((tid&63)==0) red[tid>>6] = s;
  __syncthreads();
  if (tid==0) red[4] = red[0]+red[1]+red[2]+red[3];
  __syncthreads();
  float mu = red[4] * (1.f/DM_);
  __syncthreads();
  float q = 0.f;
  for (int e=0;e<4;e++){ float d = v[e]-mu; q += d*d; }
  for (int off=32; off>0; off>>=1) q += __shfl_down(q, off, 64);
  if ((tid&63)==0) red[tid>>6] = q;
  __syncthreads();
  if (tid==0) red[4] = red[0]+red[1]+red[2]+red[3];
  __syncthreads();
  float rstd = rsqrtf(red[4]*(1.f/DM_) + 1e-5f);
  for (int e=0;e<4;e++){
    int c = tid + 256*e;
    o[(size_t)row*DM_ + c] = g[c]*(v[e]-mu)*rstd + be[c];
  }
}

// ---------------- launch ----------------
extern "C" void kernel_launch(void* const* d_in, const int* in_sizes, int n_in,
                              void* d_out, int out_size, void* d_ws, size_t ws_size,
                              hipStream_t stream)
{
  const float* x    = (const float*)d_in[0];
  const float* mem  = (const float*)d_in[1];
  const float* pos  = (const float*)d_in[2];
  const float* pbu  = (const float*)d_in[3];
  const float* pbv  = (const float*)d_in[4];
  const float* wqkv = (const float*)d_in[5];
  const float* wrel = (const float*)d_in[6];
  const float* wo   = (const float*)d_in[7];
  const float* gam  = (const float*)d_in[8];
  const float* bet  = (const float*)d_in[9];
  float* out = (float*)d_out;

  char* w = (char*)d_ws;
  unsigned short* qkvo  = (unsigned short*)(w + 0);          // 50,331,648
  unsigned short* relo  = (unsigned short*)(w + 50331648);   // 16,777,216
  unsigned short* wo16  = (unsigned short*)(w + 67108864);   //  2,097,152
  unsigned short* QUb   = (unsigned short*)(w + 69206016);   //  8,388,608
  unsigned short* QVb   = (unsigned short*)(w + 77594624);   //  8,388,608
  unsigned short* VT    = (unsigned short*)(w + 85983232);   // 16,777,216
  unsigned short* av16  = (unsigned short*)(w + 102760448);  //  8,388,608
  float*          yf    = (float*)(w + 111149056);           // 16,777,216
  unsigned short* c16   = (unsigned short*)(w + 127926272);  // 16,777,216
  unsigned short* pos16 = (unsigned short*)(w + 144703488);  // 16,777,216
  unsigned short* wq16  = (unsigned short*)(w + 161480704);  //  6,291,456
  unsigned short* wr16  = (unsigned short*)(w + 167772160);  //  2,097,152 -> total 169,869,312

  cast_cat<<<4096, 256, 0, stream>>>(mem, x, c16, 1048576, 524288);
  cast_cat<<<4096, 256, 0, stream>>>(pos, pos, pos16, 1048576, 1048576);
  cast_cat<<<1536, 256, 0, stream>>>(wqkv, wqkv, wq16, 393216, 393216);
  cast_cat<<< 512, 256, 0, stream>>>(wrel, wrel, wr16, 131072, 131072);
  cast_cat<<< 512, 256, 0, stream>>>(wo,   wo,   wo16, 131072, 131072);

  gemm_nt<<<dim3(24,64), 256, 0, stream>>>(c16,   wq16, (void*)qkvo, nullptr, 3072, 1024, 0);
  gemm_nt<<<dim3(8,64),  256, 0, stream>>>(pos16, wr16, (void*)relo, nullptr, 1024, 1024, 0);

  scatter_quv<<<2048, 256, 0, stream>>>(qkvo, pbu, pbv, QUb, QVb);
  scatter_vt<<<dim3(64,32), 256, 0, stream>>>(qkvo, VT);

  flash_attn4<<<dim3(64,16), 256, 0, stream>>>(QUb, QVb, qkvo, VT, relo, av16);

  gemm_nt<<<dim3(8,32), 256, 0, stream>>>(av16, wo16, (void*)yf, x, 1024, 1024, 1);
  ln_kernel<<<4096, 256, 0, stream>>>(yf, gam, bet, out);
}

// Round 2
// 768.186 us; speedup vs baseline: 1.3431x; 1.3431x over previous
//
#include <hip/hip_runtime.h>

#define S_ 1024
#define M_ 1024
#define T_ 2048
#define B_ 4
#define H_ 16
#define DM_ 1024
#define DH_ 64

typedef __attribute__((ext_vector_type(8))) short s16x8;
typedef __attribute__((ext_vector_type(16))) float f32x16;

__device__ __forceinline__ unsigned short f2b(float x){
  unsigned int u = __float_as_uint(x);
  u = (u + 0x7fffu + ((u>>16)&1u)) >> 16;
  return (unsigned short)u;
}
__device__ __forceinline__ float b2f(unsigned short h){
  return __uint_as_float(((unsigned int)h)<<16);
}
__device__ __forceinline__ uint4 pack8(const float* v){
  uint4 o;
  o.x = (unsigned)f2b(v[0]) | ((unsigned)f2b(v[1])<<16);
  o.y = (unsigned)f2b(v[2]) | ((unsigned)f2b(v[3])<<16);
  o.z = (unsigned)f2b(v[4]) | ((unsigned)f2b(v[5])<<16);
  o.w = (unsigned)f2b(v[6]) | ((unsigned)f2b(v[7])<<16);
  return o;
}
__device__ __forceinline__ void glds16(const unsigned short* g, unsigned short* l){
  __builtin_amdgcn_global_load_lds((const __attribute__((address_space(1))) void*)g,
                                   (__attribute__((address_space(3))) void*)l, 16, 0, 0);
}

// ---------------- cast kernels ----------------
__global__ __launch_bounds__(256) void cast_cat(const float* __restrict__ a,
    const float* __restrict__ b, unsigned short* __restrict__ dst, int n8, int na8)
{
  int i = blockIdx.x*256 + threadIdx.x;
  if (i >= n8) return;
  const float* src = (i < na8) ? (a + (size_t)i*8) : (b + ((size_t)(i-na8))*8);
  float4 x0 = *(const float4*)src;
  float4 x1 = *(const float4*)(src+4);
  float f[8] = {x0.x,x0.y,x0.z,x0.w,x1.x,x1.y,x1.z,x1.w};
  *(uint4*)&dst[(size_t)i*8] = pack8(f);
}

// ---------------- GEMM: C[M][N] = A[M][K] @ B[N][K]^T  (bf16 in, NT) ----------------
__global__ __launch_bounds__(256) void gemm_nt(const unsigned short* __restrict__ A,
    const unsigned short* __restrict__ Bw, void* __restrict__ Cout,
    const float* __restrict__ res, int Ntot, int K, int mode)
{
  __shared__ __align__(16) unsigned short a_s[128*64];
  __shared__ __align__(16) unsigned short b_s[128*64];
  const int tid = threadIdx.x;
  const int lane = tid & 63, wave = tid >> 6;
  const int wr = wave >> 1, wc = wave & 1;
  const long m0 = (long)blockIdx.y * 128, n0 = (long)blockIdx.x * 128;
  f32x16 acc[2][2];
  for (int qa=0;qa<2;qa++) for(int qb=0;qb<2;qb++) for (int e=0;e<16;e++) acc[qa][qb][e]=0.f;
  int srow[4], scol[4];
  for (int c = 0; c < 4; c++) {
    int ch = c*256 + tid;
    srow[c] = ch >> 3;
    scol[c] = (((ch & 7) ^ (srow[c] & 7))) * 8;
  }
  for (int k0 = 0; k0 < K; k0 += 64) {
    for (int c = 0; c < 4; c++) {
      int ch = c*256 + tid;
      glds16(&A[(size_t)(m0+srow[c])*K + k0 + scol[c]], &a_s[ch*8]);
      glds16(&Bw[(size_t)(n0+srow[c])*K + k0 + scol[c]], &b_s[ch*8]);
    }
    __syncthreads();
    for (int ks = 0; ks < 4; ks++) {
      const int kb = ks*2 + (lane>>5);
      s16x8 af[2], bf[2];
      for (int q = 0; q < 2; q++) {
        int ra = wr*64 + q*32 + (lane&31);
        int rb = wc*64 + q*32 + (lane&31);
        af[q] = *(const s16x8*)&a_s[ra*64 + ((kb ^ (ra&7))<<3)];
        bf[q] = *(const s16x8*)&b_s[rb*64 + ((kb ^ (rb&7))<<3)];
      }
      for (int qr=0;qr<2;qr++)
        for (int qc2=0;qc2<2;qc2++)
          acc[qr][qc2] = __builtin_amdgcn_mfma_f32_32x32x16_bf16(af[qr], bf[qc2], acc[qr][qc2], 0,0,0);
    }
    __syncthreads();
  }
  for (int qr=0;qr<2;qr++)
    for (int qc2=0;qc2<2;qc2++)
      for (int e=0;e<16;e++){
        long row = m0 + wr*64 + qr*32 + (e&3) + 8*(e>>2) + 4*(lane>>5);
        long col = n0 + wc*64 + qc2*32 + (lane&31);
        size_t o = (size_t)row*Ntot + col;
        if (mode == 0) ((unsigned short*)Cout)[o] = f2b(acc[qr][qc2][e]);
        else           ((float*)Cout)[o] = acc[qr][qc2][e] + res[o];
      }
}

// ---------------- scatter: q + biases, per-head layout ----------------
__global__ __launch_bounds__(256) void scatter_quv(const unsigned short* __restrict__ qkvo,
   const float* __restrict__ u, const float* __restrict__ v,
   unsigned short* __restrict__ QU, unsigned short* __restrict__ QV)
{
  int gid = blockIdx.x*256 + threadIdx.x;   // B*H*S*8 = 524288
  int d0 = (gid & 7) * 8;
  int i  = (gid >> 3) & (S_-1);
  int bh = gid >> 13;
  int b = bh >> 4, h = bh & 15;
  size_t src = (size_t)((M_+i)*B_ + b)*3072 + h*64 + d0;
  uint4 q8 = *(const uint4*)&qkvo[src];
  float f[8];
  f[0]=b2f(q8.x&0xffff); f[1]=b2f(q8.x>>16); f[2]=b2f(q8.y&0xffff); f[3]=b2f(q8.y>>16);
  f[4]=b2f(q8.z&0xffff); f[5]=b2f(q8.z>>16); f[6]=b2f(q8.w&0xffff); f[7]=b2f(q8.w>>16);
  float fu[8], fv[8];
  for (int e=0;e<8;e++){ fu[e] = f[e] + u[h*64+d0+e]; fv[e] = f[e] + v[h*64+d0+e]; }
  size_t dst = ((size_t)bh*S_ + i)*64 + d0;
  *(uint4*)&QU[dst] = pack8(fu);
  *(uint4*)&QV[dst] = pack8(fv);
}

// ---------------- scatter_vt: VT[bh][d][t] = V[t][b][h][d] (LDS transpose) ----------------
__global__ __launch_bounds__(256) void scatter_vt(const unsigned short* __restrict__ qkvo,
    unsigned short* __restrict__ VT)
{
  __shared__ __align__(16) unsigned short v_s[64*72];
  const int tid = threadIdx.x;
  const int bh = blockIdx.x, b = bh>>4, h = bh&15;
  const int t0 = blockIdx.y*64;
  const unsigned short* Vg = qkvo + (size_t)b*3072 + 2048 + h*64;
  for (int c=0;c<2;c++){
    int ch = c*256 + tid;
    int r = ch>>3, off = (ch&7)*8;
    *(uint4*)&v_s[r*72+off] = *(const uint4*)&Vg[(size_t)(t0+r)*12288 + off];
  }
  __syncthreads();
  for (int c=0;c<2;c++){
    int ch = c*256 + tid;
    int d = ch>>3, toff = (ch&7)*8;
    unsigned short vals[8];
    for (int e=0;e<8;e++) vals[e] = v_s[(toff+e)*72 + d];
    uint4 pk;
    pk.x = (unsigned)vals[0] | ((unsigned)vals[1]<<16);
    pk.y = (unsigned)vals[2] | ((unsigned)vals[3]<<16);
    pk.z = (unsigned)vals[4] | ((unsigned)vals[5]<<16);
    pk.w = (unsigned)vals[6] | ((unsigned)vals[7]<<16);
    *(uint4*)&VT[((size_t)bh*64 + d)*T_ + t0 + toff] = pk;
  }
}

// ---------------- fused attention v6 ----------------
// v6 = v4 structure (synchronous staging, no register prefetch — v5's prefetch
// spilled: FETCH 58->617MB) + LDS aliasing from v5:
//   rg_s: R-window (band GEMM input) then G (band output)  [saves 16KB]
//   kp_s: K (AC input) then P (softmax probs)              [saves 9KB]
// LDS 79360 -> 53760 B => 3 blocks/CU (12 waves). Cost: dual band accumulators
// (gacc0,gacc1) live across B2 (+32 VGPR vs v4; ~145 total, under the
// __launch_bounds__(256,3) ~170 cap). T5 setprio kept around MFMA clusters.
__global__ __launch_bounds__(256,3) void flash_attn4(
    const unsigned short* __restrict__ QU, const unsigned short* __restrict__ QV,
    const unsigned short* __restrict__ qkvo, const unsigned short* __restrict__ VT,
    const unsigned short* __restrict__ relo, unsigned short* __restrict__ AV)
{
  __shared__ __align__(16) unsigned short qu_s[64*72];
  __shared__ __align__(16) unsigned short qv_s[65*72];
  __shared__ __align__(16) unsigned short kp_s[64*72];   // K during AC, then P
  __shared__ __align__(16) unsigned short vT_s[64*72];
  __shared__ __align__(16) unsigned short rg_s[64*128];  // R window (XOR slots), then G
  __shared__ float l_s[64];

  const int tid = threadIdx.x, lane = tid&63, wave = tid>>6;
  const int bh = blockIdx.x, b = bh>>4, h = bh&15;
  const int i0 = blockIdx.y*64;
  const int qr = wave>>1, qc = wave&1;
  const unsigned short* QUb = QU + (size_t)bh*S_*DH_;
  const unsigned short* QVb = QV + (size_t)bh*S_*DH_;
  const unsigned short* Kg  = qkvo + (size_t)b*3072 + 1024 + h*64;   // + t*12288
  const unsigned short* VTb = VT + (size_t)bh*64*T_;
  const unsigned short* Rg  = relo + (size_t)b*1024 + h*64;          // + t*4096

  // stage QU rows i0..i0+63 and QV rows i0..i0+64 (65 rows; +64 clamped)
  for (int c=0;c<2;c++){
    int ch = c*256+tid; int row = ch>>3, off=(ch&7)*8;
    *(uint4*)&qu_s[row*72+off] = *(const uint4*)&QUb[(size_t)(i0+row)*64 + off];
    *(uint4*)&qv_s[row*72+off] = *(const uint4*)&QVb[(size_t)(i0+row)*64 + off];
  }
  if (tid < 8) {
    int rr = i0 + 64; if (rr > S_-1) rr = S_-1;
    *(uint4*)&qv_s[64*72 + tid*8] = *(const uint4*)&QVb[(size_t)rr*64 + tid*8];
  }

  f32x16 acc_o;
  for (int e=0;e<16;e++) acc_o[e]=0.f;
  float lreg = 0.f;

  const int col = qc*32 + (lane&31);
  const int rbase = qr*32 + 4*(lane>>5);

  for (int j0 = 0; j0 < T_; j0 += 64) {
    const int jdmax = j0 + 63 - i0;
    const int jdmin = j0 - 63 - i0;
    const int cls = (jdmax <= 1024) ? 0 : ((jdmin >= 1026) ? 2 : 1);
    const int wb = (cls == 2) ? (j0 - i0 - 1089) : (j0 - i0 + 960);
    const int ashift = (cls == 2) ? 1 : 0;

    // stage K -> kp_s, VT -> vT_s (padded-72), R window -> rg_s (XOR slots).
    // Previous iteration's readers of these buffers finished at B5.
    for (int c=0;c<2;c++){
      int ch = c*256+tid; int row = ch>>3, off=(ch&7)*8;
      *(uint4*)&kp_s[row*72+off] = *(const uint4*)&Kg[(size_t)(j0+row)*12288 + off];
      *(uint4*)&vT_s[row*72+off] = *(const uint4*)&VTb[(size_t)row*T_ + j0 + off];
    }
    for (int c=0;c<4;c++){
      int ch = c*256+tid; int rr = ch>>3, off = ch&7;
      int t = wb + rr; t = t < 0 ? 0 : (t > T_-1 ? T_-1 : t);
      *(uint4*)&rg_s[rr*64 + ((off ^ (rr&7))<<3)] = *(const uint4*)&Rg[(size_t)t*4096 + off*8];
    }
    __syncthreads();           // B1: staging visible

    // band GEMM: 2 quads per wave, results kept in regs until after B2
    f32x16 gacc0, gacc1;
    for (int e=0;e<16;e++){ gacc0[e]=0.f; gacc1[e]=0.f; }
    __builtin_amdgcn_s_setprio(1);
    for (int ks=0; ks<4; ks++){
      int koff = ks*16 + (lane>>5)*8, kb = ks*2 + (lane>>5);
      int ar = qr*32 + (lane&31) + ashift;
      s16x8 a  = *(const s16x8*)&qv_s[ar*72 + koff];
      {
        int br = (qc*2+0)*32 + (lane&31);
        s16x8 bb = *(const s16x8*)&rg_s[br*64 + ((kb ^ (br&7))<<3)];
        gacc0 = __builtin_amdgcn_mfma_f32_32x32x16_bf16(a, bb, gacc0, 0,0,0);
      }
      {
        int br = (qc*2+1)*32 + (lane&31);
        s16x8 bb = *(const s16x8*)&rg_s[br*64 + ((kb ^ (br&7))<<3)];
        gacc1 = __builtin_amdgcn_mfma_f32_32x32x16_bf16(a, bb, gacc1, 0,0,0);
      }
    }
    // AC quad (reads kp_s = K)
    f32x16 acc;
    for (int e=0;e<16;e++) acc[e]=0.f;
    for (int ks=0; ks<4; ks++){
      int koff = ks*16 + (lane>>5)*8;
      s16x8 a  = *(const s16x8*)&qu_s[(qr*32+(lane&31))*72 + koff];
      s16x8 bq = *(const s16x8*)&kp_s[(qc*32+(lane&31))*72 + koff];
      acc = __builtin_amdgcn_mfma_f32_32x32x16_bf16(a, bq, acc, 0,0,0);
    }
    __builtin_amdgcn_s_setprio(0);
    __syncthreads();           // B2: all reads of rg_s(R) and kp_s(K) complete

    // write G into rg_s (aliases dead R window)
    for (int e=0;e<16;e++){
      int r = rbase + (e&3) + 8*(e>>2);
      rg_s[r*128 + (qc*2+0)*32 + (lane&31)] = f2b(gacc0[e]);
      rg_s[r*128 + (qc*2+1)*32 + (lane&31)] = f2b(gacc1[e]);
    }
    __syncthreads();           // B3: G visible

    // assembly phase A (all of cls 0/2; jd<=1025 part of cls 1) -> P into kp_s
    for (int e=0;e<16;e++){
      int r = rbase + (e&3) + 8*(e>>2);
      int jd = j0 + col - (i0 + r);
      if (cls == 1 && jd >= 1026) continue;
      float bd = (jd == 1025) ? 0.f : b2f(rg_s[r*128 + (col - r + 63)]);
      kp_s[r*72 + col] = f2b(__expf((acc[e] + bd) * 0.125f));
    }
    if (cls == 1) {
      __syncthreads();         // C1: G reads done -> can overwrite rg_s
      const int wb2 = j0 - i0 - 1089;
      for (int c=0;c<4;c++){
        int ch = c*256+tid; int rr = ch>>3, off = ch&7;
        int t = wb2 + rr; t = t < 0 ? 0 : (t > T_-1 ? T_-1 : t);
        *(uint4*)&rg_s[rr*64 + ((off ^ (rr&7))<<3)] = *(const uint4*)&Rg[(size_t)t*4096 + off*8];
      }
      __syncthreads();         // C2: wrap R window visible
      f32x16 g2a, g2b;
      for (int e=0;e<16;e++){ g2a[e]=0.f; g2b[e]=0.f; }
      __builtin_amdgcn_s_setprio(1);
      for (int ks=0; ks<4; ks++){
        int koff = ks*16 + (lane>>5)*8, kb = ks*2 + (lane>>5);
        int ar = qr*32 + (lane&31) + 1;    // wrap band uses QV[i+1]
        s16x8 a  = *(const s16x8*)&qv_s[ar*72 + koff];
        {
          int br = (qc*2+0)*32 + (lane&31);
          s16x8 bb = *(const s16x8*)&rg_s[br*64 + ((kb ^ (br&7))<<3)];
          g2a = __builtin_amdgcn_mfma_f32_32x32x16_bf16(a, bb, g2a, 0,0,0);
        }
        {
          int br = (qc*2+1)*32 + (lane&31);
          s16x8 bb = *(const s16x8*)&rg_s[br*64 + ((kb ^ (br&7))<<3)];
          g2b = __builtin_amdgcn_mfma_f32_32x32x16_bf16(a, bb, g2b, 0,0,0);
        }
      }
      __builtin_amdgcn_s_setprio(0);
      __syncthreads();         // C3: wrap R reads done
      for (int e=0;e<16;e++){
        int r = rbase + (e&3) + 8*(e>>2);
        rg_s[r*128 + (qc*2+0)*32 + (lane&31)] = f2b(g2a[e]);
        rg_s[r*128 + (qc*2+1)*32 + (lane&31)] = f2b(g2b[e]);
      }
      __syncthreads();         // C4: G2 visible
      for (int e=0;e<16;e++){
        int r = rbase + (e&3) + 8*(e>>2);
        int jd = j0 + col - (i0 + r);
        if (jd < 1026) continue;
        float bd = b2f(rg_s[r*128 + (col - r + 63)]);
        kp_s[r*72 + col] = f2b(__expf((acc[e] + bd) * 0.125f));
      }
    }
    __syncthreads();           // B4: P visible

    // rowsum (4 threads per row) from kp_s (= P)
    {
      int rr = tid>>2, cb = (tid&3)*16;
      uint4 x0 = *(const uint4*)&kp_s[rr*72+cb];
      uint4 x1 = *(const uint4*)&kp_s[rr*72+cb+8];
      unsigned vs[8] = {x0.x,x0.y,x0.z,x0.w,x1.x,x1.y,x1.z,x1.w};
      float s = 0.f;
      for (int e=0;e<8;e++) s += b2f((unsigned short)(vs[e]&0xffff)) + b2f((unsigned short)(vs[e]>>16));
      s += __shfl_xor(s, 1, 64);
      s += __shfl_xor(s, 2, 64);
      if ((tid&3)==0) lreg += s;
    }
    // PV quad
    __builtin_amdgcn_s_setprio(1);
    for (int ks=0; ks<4; ks++){
      int koff = ks*16 + (lane>>5)*8;
      s16x8 a  = *(const s16x8*)&kp_s[(qr*32+(lane&31))*72 + koff];
      s16x8 bv = *(const s16x8*)&vT_s[(qc*32+(lane&31))*72 + koff];
      acc_o = __builtin_amdgcn_mfma_f32_32x32x16_bf16(a, bv, acc_o, 0,0,0);
    }
    __builtin_amdgcn_s_setprio(0);
    __syncthreads();           // B5: kp_s(P)/vT_s/rg_s reads done -> next stage safe
  }

  if ((tid&3)==0) l_s[tid>>2] = lreg;
  __syncthreads();
  for (int e=0;e<16;e++){
    int r = rbase + (e&3) + 8*(e>>2);
    float oo = acc_o[e] / l_s[r];
    AV[ ((size_t)(i0+r)*B_ + b)*(H_*DH_) + h*DH_ + col ] = f2b(oo);
  }
}

// ---------------- LayerNorm ----------------
__global__ __launch_bounds__(256) void ln_kernel(const float* __restrict__ y,
    const float* __restrict__ g, const float* __restrict__ be, float* __restrict__ o)
{
  __shared__ float red[8];
  int row = blockIdx.x, tid = threadIdx.x;
  const float* yr = y + (size_t)row*DM_;
  float v[4];
  for (int e=0;e<4;e++) v[e] = yr[tid + 256*e];
  float s = v[0]+v[1]+v[2]+v[3];
  for (int off=32; off>0; off>>=1) s += __shfl_down(s, off, 64);
  if ((tid&63)==0) red[tid>>6] = s;
  __syncthreads();
  if (tid==0) red[4] = red[0]+red[1]+red[2]+red[3];
  __syncthreads();
  float mu = red[4] * (1.f/DM_);
  __syncthreads();
  float q = 0.f;
  for (int e=0;e<4;e++){ float d = v[e]-mu; q += d*d; }
  for (int off=32; off>0; off>>=1) q += __shfl_down(q, off, 64);
  if ((tid&63)==0) red[tid>>6] = q;
  __syncthreads();
  if (tid==0) red[4] = red[0]+red[1]+red[2]+red[3];
  __syncthreads();
  float rstd = rsqrtf(red[4]*(1.f/DM_) + 1e-5f);
  for (int e=0;e<4;e++){
    int c = tid + 256*e;
    o[(size_t)row*DM_ + c] = g[c]*(v[e]-mu)*rstd + be[c];
  }
}

// ---------------- launch ----------------
extern "C" void kernel_launch(void* const* d_in, const int* in_sizes, int n_in,
                              void* d_out, int out_size, void* d_ws, size_t ws_size,
                              hipStream_t stream)
{
  const float* x    = (const float*)d_in[0];
  const float* mem  = (const float*)d_in[1];
  const float* pos  = (const float*)d_in[2];
  const float* pbu  = (const float*)d_in[3];
  const float* pbv  = (const float*)d_in[4];
  const float* wqkv = (const float*)d_in[5];
  const float* wrel = (const float*)d_in[6];
  const float* wo   = (const float*)d_in[7];
  const float* gam  = (const float*)d_in[8];
  const float* bet  = (const float*)d_in[9];
  float* out = (float*)d_out;

  char* w = (char*)d_ws;
  unsigned short* qkvo  = (unsigned short*)(w + 0);          // 50,331,648
  unsigned short* relo  = (unsigned short*)(w + 50331648);   // 16,777,216
  unsigned short* wo16  = (unsigned short*)(w + 67108864);   //  2,097,152
  unsigned short* QUb   = (unsigned short*)(w + 69206016);   //  8,388,608
  unsigned short* QVb   = (unsigned short*)(w + 77594624);   //  8,388,608
  unsigned short* VT    = (unsigned short*)(w + 85983232);   // 16,777,216
  unsigned short* av16  = (unsigned short*)(w + 102760448);  //  8,388,608
  float*          yf    = (float*)(w + 111149056);           // 16,777,216
  unsigned short* c16   = (unsigned short*)(w + 127926272);  // 16,777,216
  unsigned short* pos16 = (unsigned short*)(w + 144703488);  // 16,777,216
  unsigned short* wq16  = (unsigned short*)(w + 161480704);  //  6,291,456
  unsigned short* wr16  = (unsigned short*)(w + 167772160);  //  2,097,152 -> total 169,869,312

  cast_cat<<<4096, 256, 0, stream>>>(mem, x, c16, 1048576, 524288);
  cast_cat<<<4096, 256, 0, stream>>>(pos, pos, pos16, 1048576, 1048576);
  cast_cat<<<1536, 256, 0, stream>>>(wqkv, wqkv, wq16, 393216, 393216);
  cast_cat<<< 512, 256, 0, stream>>>(wrel, wrel, wr16, 131072, 131072);
  cast_cat<<< 512, 256, 0, stream>>>(wo,   wo,   wo16, 131072, 131072);

  gemm_nt<<<dim3(24,64), 256, 0, stream>>>(c16,   wq16, (void*)qkvo, nullptr, 3072, 1024, 0);
  gemm_nt<<<dim3(8,64),  256, 0, stream>>>(pos16, wr16, (void*)relo, nullptr, 1024, 1024, 0);

  scatter_quv<<<2048, 256, 0, stream>>>(qkvo, pbu, pbv, QUb, QVb);
  scatter_vt<<<dim3(64,32), 256, 0, stream>>>(qkvo, VT);

  flash_attn4<<<dim3(64,16), 256, 0, stream>>>(QUb, QVb, qkvo, VT, relo, av16);

  gemm_nt<<<dim3(8,32), 256, 0, stream>>>(av16, wo16, (void*)yf, x, 1024, 1024, 1);
  ln_kernel<<<4096, 256, 0, stream>>>(yf, gam, bet, out);
}

// Round 3
// 522.519 us; speedup vs baseline: 1.9745x; 1.4702x over previous
//
#include <hip/hip_runtime.h>

#define S_ 1024
#define M_ 1024
#define T_ 2048
#define B_ 4
#define H_ 16
#define DM_ 1024
#define DH_ 64

typedef __attribute__((ext_vector_type(8))) short s16x8;
typedef __attribute__((ext_vector_type(16))) float f32x16;

__device__ __forceinline__ unsigned short f2b(float x){
  unsigned int u = __float_as_uint(x);
  u = (u + 0x7fffu + ((u>>16)&1u)) >> 16;
  return (unsigned short)u;
}
__device__ __forceinline__ float b2f(unsigned short h){
  return __uint_as_float(((unsigned int)h)<<16);
}
__device__ __forceinline__ uint4 pack8(const float* v){
  uint4 o;
  o.x = (unsigned)f2b(v[0]) | ((unsigned)f2b(v[1])<<16);
  o.y = (unsigned)f2b(v[2]) | ((unsigned)f2b(v[3])<<16);
  o.z = (unsigned)f2b(v[4]) | ((unsigned)f2b(v[5])<<16);
  o.w = (unsigned)f2b(v[6]) | ((unsigned)f2b(v[7])<<16);
  return o;
}
__device__ __forceinline__ void glds16(const unsigned short* g, unsigned short* l){
  __builtin_amdgcn_global_load_lds((const __attribute__((address_space(1))) void*)g,
                                   (__attribute__((address_space(3))) void*)l, 16, 0, 0);
}

// raw barriers: BAR_L waits only LDS ops (leaves glds prefetches in flight);
// BAR_VL additionally drains vmcnt (loop-top, after prefetches had a full
// iteration to land).
#define BAR_L()  asm volatile("s_waitcnt lgkmcnt(0)\ns_barrier" ::: "memory")
#define BAR_VL() asm volatile("s_waitcnt vmcnt(0) lgkmcnt(0)\ns_barrier" ::: "memory")

// ---------------- cast kernels ----------------
__global__ __launch_bounds__(256) void cast_cat(const float* __restrict__ a,
    const float* __restrict__ b, unsigned short* __restrict__ dst, int n8, int na8)
{
  int i = blockIdx.x*256 + threadIdx.x;
  if (i >= n8) return;
  const float* src = (i < na8) ? (a + (size_t)i*8) : (b + ((size_t)(i-na8))*8);
  float4 x0 = *(const float4*)src;
  float4 x1 = *(const float4*)(src+4);
  float f[8] = {x0.x,x0.y,x0.z,x0.w,x1.x,x1.y,x1.z,x1.w};
  *(uint4*)&dst[(size_t)i*8] = pack8(f);
}

// ---------------- GEMM: C[M][N] = A[M][K] @ B[N][K]^T  (bf16 in, NT) ----------------
__global__ __launch_bounds__(256) void gemm_nt(const unsigned short* __restrict__ A,
    const unsigned short* __restrict__ Bw, void* __restrict__ Cout,
    const float* __restrict__ res, int Ntot, int K, int mode)
{
  __shared__ __align__(16) unsigned short a_s[128*64];
  __shared__ __align__(16) unsigned short b_s[128*64];
  const int tid = threadIdx.x;
  const int lane = tid & 63, wave = tid >> 6;
  const int wr = wave >> 1, wc = wave & 1;
  const long m0 = (long)blockIdx.y * 128, n0 = (long)blockIdx.x * 128;
  f32x16 acc[2][2];
  for (int qa=0;qa<2;qa++) for(int qb=0;qb<2;qb++) for (int e=0;e<16;e++) acc[qa][qb][e]=0.f;
  int srow[4], scol[4];
  for (int c = 0; c < 4; c++) {
    int ch = c*256 + tid;
    srow[c] = ch >> 3;
    scol[c] = (((ch & 7) ^ (srow[c] & 7))) * 8;
  }
  for (int k0 = 0; k0 < K; k0 += 64) {
    for (int c = 0; c < 4; c++) {
      int ch = c*256 + tid;
      glds16(&A[(size_t)(m0+srow[c])*K + k0 + scol[c]], &a_s[ch*8]);
      glds16(&Bw[(size_t)(n0+srow[c])*K + k0 + scol[c]], &b_s[ch*8]);
    }
    __syncthreads();
    for (int ks = 0; ks < 4; ks++) {
      const int kb = ks*2 + (lane>>5);
      s16x8 af[2], bf[2];
      for (int q = 0; q < 2; q++) {
        int ra = wr*64 + q*32 + (lane&31);
        int rb = wc*64 + q*32 + (lane&31);
        af[q] = *(const s16x8*)&a_s[ra*64 + ((kb ^ (ra&7))<<3)];
        bf[q] = *(const s16x8*)&b_s[rb*64 + ((kb ^ (rb&7))<<3)];
      }
      for (int qr=0;qr<2;qr++)
        for (int qc2=0;qc2<2;qc2++)
          acc[qr][qc2] = __builtin_amdgcn_mfma_f32_32x32x16_bf16(af[qr], bf[qc2], acc[qr][qc2], 0,0,0);
    }
    __syncthreads();
  }
  for (int qr=0;qr<2;qr++)
    for (int qc2=0;qc2<2;qc2++)
      for (int e=0;e<16;e++){
        long row = m0 + wr*64 + qr*32 + (e&3) + 8*(e>>2) + 4*(lane>>5);
        long col = n0 + wc*64 + qc2*32 + (lane&31);
        size_t o = (size_t)row*Ntot + col;
        if (mode == 0) ((unsigned short*)Cout)[o] = f2b(acc[qr][qc2][e]);
        else           ((float*)Cout)[o] = acc[qr][qc2][e] + res[o];
      }
}

// ---------------- scatter: q + biases, per-head layout ----------------
__global__ __launch_bounds__(256) void scatter_quv(const unsigned short* __restrict__ qkvo,
   const float* __restrict__ u, const float* __restrict__ v,
   unsigned short* __restrict__ QU, unsigned short* __restrict__ QV)
{
  int gid = blockIdx.x*256 + threadIdx.x;   // B*H*S*8 = 524288
  int d0 = (gid & 7) * 8;
  int i  = (gid >> 3) & (S_-1);
  int bh = gid >> 13;
  int b = bh >> 4, h = bh & 15;
  size_t src = (size_t)((M_+i)*B_ + b)*3072 + h*64 + d0;
  uint4 q8 = *(const uint4*)&qkvo[src];
  float f[8];
  f[0]=b2f(q8.x&0xffff); f[1]=b2f(q8.x>>16); f[2]=b2f(q8.y&0xffff); f[3]=b2f(q8.y>>16);
  f[4]=b2f(q8.z&0xffff); f[5]=b2f(q8.z>>16); f[6]=b2f(q8.w&0xffff); f[7]=b2f(q8.w>>16);
  float fu[8], fv[8];
  for (int e=0;e<8;e++){ fu[e] = f[e] + u[h*64+d0+e]; fv[e] = f[e] + v[h*64+d0+e]; }
  size_t dst = ((size_t)bh*S_ + i)*64 + d0;
  *(uint4*)&QU[dst] = pack8(fu);
  *(uint4*)&QV[dst] = pack8(fv);
}

// ---------------- scatter_vt: VT[bh][d][t] = V[t][b][h][d] (LDS transpose) ----------------
__global__ __launch_bounds__(256) void scatter_vt(const unsigned short* __restrict__ qkvo,
    unsigned short* __restrict__ VT)
{
  __shared__ __align__(16) unsigned short v_s[64*72];
  const int tid = threadIdx.x;
  const int bh = blockIdx.x, b = bh>>4, h = bh&15;
  const int t0 = blockIdx.y*64;
  const unsigned short* Vg = qkvo + (size_t)b*3072 + 2048 + h*64;
  for (int c=0;c<2;c++){
    int ch = c*256 + tid;
    int r = ch>>3, off = (ch&7)*8;
    *(uint4*)&v_s[r*72+off] = *(const uint4*)&Vg[(size_t)(t0+r)*12288 + off];
  }
  __syncthreads();
  for (int c=0;c<2;c++){
    int ch = c*256 + tid;
    int d = ch>>3, toff = (ch&7)*8;
    unsigned short vals[8];
    for (int e=0;e<8;e++) vals[e] = v_s[(toff+e)*72 + d];
    uint4 pk;
    pk.x = (unsigned)vals[0] | ((unsigned)vals[1]<<16);
    pk.y = (unsigned)vals[2] | ((unsigned)vals[3]<<16);
    pk.z = (unsigned)vals[4] | ((unsigned)vals[5]<<16);
    pk.w = (unsigned)vals[6] | ((unsigned)vals[7]<<16);
    *(uint4*)&VT[((size_t)bh*64 + d)*T_ + t0 + toff] = pk;
  }
}

// ---------------- fused attention v7 ----------------
// v7 = v4 structure at __launch_bounds__(256,2) (rounds 1-2 showed (256,3)
// caps unified regs at ~170 -> spills), with async DMA staging (T3/T4-lite):
//   * K/VT/R staged via global_load_lds (no data regs, unlike the failed v5
//     register prefetch). LDS dest linear; XOR bank-swizzle moved to the
//     per-lane GLOBAL source address (m173 / gemm_nt pattern).
//   * Prefetch issue points: VT(next) after B1 (VT consumed end-of-iter,
//     double-buffered); K(next) after B2 (K consumed at AC); R(next) after B4
//     (G in rg_s consumed by assembly).
//   * Intra-iter barriers are raw s_barrier + lgkmcnt(0) only -> glds
//     prefetches stay in flight across them. Only the loop-top barrier
//     drains vmcnt(0), by which point prefetches had ~a full iter to land.
//   * B5 removed (loop-top barrier subsumes it): 4 barriers/iter, 1 vm drain.
// LDS: qu 9216 + qv 9360 + K 8192 + VT 2x8192 + RG 16384 + P 9216 + l 256
//   = 69008 B -> 2 blocks/CU.
__global__ __launch_bounds__(256,2) void flash_attn4(
    const unsigned short* __restrict__ QU, const unsigned short* __restrict__ QV,
    const unsigned short* __restrict__ qkvo, const unsigned short* __restrict__ VT,
    const unsigned short* __restrict__ relo, unsigned short* __restrict__ AV)
{
  __shared__ __align__(16) unsigned short qu_s[64*72];
  __shared__ __align__(16) unsigned short qv_s[65*72];
  __shared__ __align__(16) unsigned short k_s [64*64];      // XOR-64 layout
  __shared__ __align__(16) unsigned short vt_s[2][64*64];   // XOR-64, double-buffered
  __shared__ __align__(16) unsigned short rg_s[128*64];     // R window (XOR) then G
  __shared__ __align__(16) unsigned short p_s [64*72];
  __shared__ float l_s[64];

  const int tid = threadIdx.x, lane = tid&63, wave = tid>>6;
  const int bh = blockIdx.x, b = bh>>4, h = bh&15;
  const int i0 = blockIdx.y*64;
  const int qr = wave>>1, qc = wave&1;
  const unsigned short* QUb = QU + (size_t)bh*S_*DH_;
  const unsigned short* QVb = QV + (size_t)bh*S_*DH_;
  const unsigned short* Kg  = qkvo + (size_t)b*3072 + 1024 + h*64;   // + t*12288
  const unsigned short* VTb = VT + (size_t)bh*64*T_;
  const unsigned short* Rg  = relo + (size_t)b*1024 + h*64;          // + t*4096

  // per-thread staging geometry (2-chunk tiles: K, VT)
  const int s0r = tid>>3,        s0c = (((tid&7)       ^ (s0r&7)))*8;
  const int s1r = (256+tid)>>3,  s1c = ((((256+tid)&7) ^ (s1r&7)))*8;

  int vb = 0;

  // ---- prologue: issue DMA for tile 0, plain-stage QU/QV ----
  glds16(&Kg [(size_t)(0+s0r)*12288 + s0c], &k_s[(size_t)tid*8]);
  glds16(&Kg [(size_t)(0+s1r)*12288 + s1c], &k_s[(size_t)(256+tid)*8]);
  glds16(&VTb[(size_t)s0r*T_ + 0 + s0c],    &vt_s[0][(size_t)tid*8]);
  glds16(&VTb[(size_t)s1r*T_ + 0 + s1c],    &vt_s[0][(size_t)(256+tid)*8]);
  {
    const int wb0 = 0 - i0 + 960;    // j0=0 is always cls 0
    for (int c=0;c<4;c++){
      int ch = c*256+tid; int rr = ch>>3, off = ch&7;
      int t = wb0 + rr; t = t < 0 ? 0 : (t > T_-1 ? T_-1 : t);
      int sc = ((off ^ (rr&7)))*8;
      glds16(&Rg[(size_t)t*4096 + sc], &rg_s[(size_t)ch*8]);
    }
  }
  for (int c=0;c<2;c++){
    int ch = c*256+tid; int row = ch>>3, off=(ch&7)*8;
    *(uint4*)&qu_s[row*72+off] = *(const uint4*)&QUb[(size_t)(i0+row)*64 + off];
    *(uint4*)&qv_s[row*72+off] = *(const uint4*)&QVb[(size_t)(i0+row)*64 + off];
  }
  if (tid < 8) {
    int rr = i0 + 64; if (rr > S_-1) rr = S_-1;
    *(uint4*)&qv_s[64*72 + tid*8] = *(const uint4*)&QVb[(size_t)rr*64 + tid*8];
  }

  f32x16 acc_o;
  for (int e=0;e<16;e++) acc_o[e]=0.f;
  float lreg = 0.f;

  const int col = qc*32 + (lane&31);
  const int rbase = qr*32 + 4*(lane>>5);

  for (int j0 = 0; j0 < T_; j0 += 64) {
    const int jdmax = j0 + 63 - i0;
    const int jdmin = j0 - 63 - i0;
    const int cls = (jdmax <= 1024) ? 0 : ((jdmin >= 1026) ? 2 : 1);
    const int ashift = (cls == 2) ? 1 : 0;
    const int jn = j0 + 64;

    BAR_VL();                  // B1: all staged data (DMA + plain) visible

    // prefetch VT(next) into the other buffer (consumed at next iter's PV)
    if (jn < T_) {
      glds16(&VTb[(size_t)s0r*T_ + jn + s0c], &vt_s[vb^1][(size_t)tid*8]);
      glds16(&VTb[(size_t)s1r*T_ + jn + s1c], &vt_s[vb^1][(size_t)(256+tid)*8]);
    }

    // band GEMM: 2 quads per wave (reads rg_s=R, qv_s)
    f32x16 gacc0, gacc1;
    for (int e=0;e<16;e++){ gacc0[e]=0.f; gacc1[e]=0.f; }
    __builtin_amdgcn_s_setprio(1);
    for (int ks=0; ks<4; ks++){
      int koff = ks*16 + (lane>>5)*8, kb = ks*2 + (lane>>5);
      int ar = qr*32 + (lane&31) + ashift;
      s16x8 a  = *(const s16x8*)&qv_s[ar*72 + koff];
      {
        int br = (qc*2+0)*32 + (lane&31);
        s16x8 bb = *(const s16x8*)&rg_s[br*64 + ((kb ^ (br&7))<<3)];
        gacc0 = __builtin_amdgcn_mfma_f32_32x32x16_bf16(a, bb, gacc0, 0,0,0);
      }
      {
        int br = (qc*2+1)*32 + (lane&31);
        s16x8 bb = *(const s16x8*)&rg_s[br*64 + ((kb ^ (br&7))<<3)];
        gacc1 = __builtin_amdgcn_mfma_f32_32x32x16_bf16(a, bb, gacc1, 0,0,0);
      }
    }
    // AC quad (reads qu_s, k_s=K in XOR-64 layout)
    f32x16 acc;
    for (int e=0;e<16;e++) acc[e]=0.f;
    for (int ks=0; ks<4; ks++){
      int koff = ks*16 + (lane>>5)*8, kb = ks*2 + (lane>>5);
      int rbk = qc*32 + (lane&31);
      s16x8 a  = *(const s16x8*)&qu_s[(qr*32+(lane&31))*72 + koff];
      s16x8 bq = *(const s16x8*)&k_s[rbk*64 + ((kb ^ (rbk&7))<<3)];
      acc = __builtin_amdgcn_mfma_f32_32x32x16_bf16(a, bq, acc, 0,0,0);
    }
    __builtin_amdgcn_s_setprio(0);
    BAR_L();                   // B2: R and K consumed

    // prefetch K(next) (K buffer free after B2; consumed next iter phase 1)
    if (jn < T_) {
      glds16(&Kg[(size_t)(jn+s0r)*12288 + s0c], &k_s[(size_t)tid*8]);
      glds16(&Kg[(size_t)(jn+s1r)*12288 + s1c], &k_s[(size_t)(256+tid)*8]);
    }

    // write G into rg_s (aliases dead R window)
    for (int e=0;e<16;e++){
      int r = rbase + (e&3) + 8*(e>>2);
      rg_s[r*128 + (qc*2+0)*32 + (lane&31)] = f2b(gacc0[e]);
      rg_s[r*128 + (qc*2+1)*32 + (lane&31)] = f2b(gacc1[e]);
    }
    BAR_L();                   // B3: G visible

    // assembly phase A (all of cls 0/2; jd<=1025 part of cls 1) -> P
    for (int e=0;e<16;e++){
      int r = rbase + (e&3) + 8*(e>>2);
      int jd = j0 + col - (i0 + r);
      if (cls == 1 && jd >= 1026) continue;
      float bd = (jd == 1025) ? 0.f : b2f(rg_s[r*128 + (col - r + 63)]);
      p_s[r*72 + col] = f2b(__expf((acc[e] + bd) * 0.125f));
    }
    if (cls == 1) {
      BAR_L();                 // C1: G reads done -> can overwrite rg_s
      const int wb2 = j0 - i0 - 1089;
      for (int c=0;c<4;c++){
        int ch = c*256+tid; int rr = ch>>3, off = ch&7;
        int t = wb2 + rr; t = t < 0 ? 0 : (t > T_-1 ? T_-1 : t);
        *(uint4*)&rg_s[rr*64 + ((off ^ (rr&7))<<3)] = *(const uint4*)&Rg[(size_t)t*4096 + off*8];
      }
      BAR_L();                 // C2: wrap R window visible
      f32x16 g2a, g2b;
      for (int e=0;e<16;e++){ g2a[e]=0.f; g2b[e]=0.f; }
      __builtin_amdgcn_s_setprio(1);
      for (int ks=0; ks<4; ks++){
        int koff = ks*16 + (lane>>5)*8, kb = ks*2 + (lane>>5);
        int ar = qr*32 + (lane&31) + 1;    // wrap band uses QV[i+1]
        s16x8 a  = *(const s16x8*)&qv_s[ar*72 + koff];
        {
          int br = (qc*2+0)*32 + (lane&31);
          s16x8 bb = *(const s16x8*)&rg_s[br*64 + ((kb ^ (br&7))<<3)];
          g2a = __builtin_amdgcn_mfma_f32_32x32x16_bf16(a, bb, g2a, 0,0,0);
        }
        {
          int br = (qc*2+1)*32 + (lane&31);
          s16x8 bb = *(const s16x8*)&rg_s[br*64 + ((kb ^ (br&7))<<3)];
          g2b = __builtin_amdgcn_mfma_f32_32x32x16_bf16(a, bb, g2b, 0,0,0);
        }
      }
      __builtin_amdgcn_s_setprio(0);
      BAR_L();                 // C3: wrap R reads done
      for (int e=0;e<16;e++){
        int r = rbase + (e&3) + 8*(e>>2);
        rg_s[r*128 + (qc*2+0)*32 + (lane&31)] = f2b(g2a[e]);
        rg_s[r*128 + (qc*2+1)*32 + (lane&31)] = f2b(g2b[e]);
      }
      BAR_L();                 // C4: G2 visible
      for (int e=0;e<16;e++){
        int r = rbase + (e&3) + 8*(e>>2);
        int jd = j0 + col - (i0 + r);
        if (jd < 1026) continue;
        float bd = b2f(rg_s[r*128 + (col - r + 63)]);
        p_s[r*72 + col] = f2b(__expf((acc[e] + bd) * 0.125f));
      }
    }
    BAR_L();                   // B4: P visible; G (rg_s) fully consumed

    // prefetch R(next) into rg_s (consumed at next iter's band GEMM)
    if (jn < T_) {
      const int jdmaxn = jn + 63 - i0;
      const int jdminn = jn - 63 - i0;
      const int clsn = (jdmaxn <= 1024) ? 0 : ((jdminn >= 1026) ? 2 : 1);
      const int wbn = (clsn == 2) ? (jn - i0 - 1089) : (jn - i0 + 960);
      for (int c=0;c<4;c++){
        int ch = c*256+tid; int rr = ch>>3, off = ch&7;
        int t = wbn + rr; t = t < 0 ? 0 : (t > T_-1 ? T_-1 : t);
        int sc = ((off ^ (rr&7)))*8;
        glds16(&Rg[(size_t)t*4096 + sc], &rg_s[(size_t)ch*8]);
      }
    }

    // rowsum (4 threads per row) from p_s
    {
      int rr = tid>>2, cb = (tid&3)*16;
      uint4 x0 = *(const uint4*)&p_s[rr*72+cb];
      uint4 x1 = *(const uint4*)&p_s[rr*72+cb+8];
      unsigned vs[8] = {x0.x,x0.y,x0.z,x0.w,x1.x,x1.y,x1.z,x1.w};
      float s = 0.f;
      for (int e=0;e<8;e++) s += b2f((unsigned short)(vs[e]&0xffff)) + b2f((unsigned short)(vs[e]>>16));
      s += __shfl_xor(s, 1, 64);
      s += __shfl_xor(s, 2, 64);
      if ((tid&3)==0) lreg += s;
    }
    // PV quad (reads p_s, vt_s[vb] in XOR-64 layout)
    __builtin_amdgcn_s_setprio(1);
    for (int ks=0; ks<4; ks++){
      int koff = ks*16 + (lane>>5)*8, kb = ks*2 + (lane>>5);
      int rbv = qc*32 + (lane&31);
      s16x8 a  = *(const s16x8*)&p_s[(qr*32+(lane&31))*72 + koff];
      s16x8 bv = *(const s16x8*)&vt_s[vb][rbv*64 + ((kb ^ (rbv&7))<<3)];
      acc_o = __builtin_amdgcn_mfma_f32_32x32x16_bf16(a, bv, acc_o, 0,0,0);
    }
    __builtin_amdgcn_s_setprio(0);
    vb ^= 1;
    // no B5: loop-top BAR_VL() orders everything for the next iteration
  }

  if ((tid&3)==0) l_s[tid>>2] = lreg;
  BAR_L();
  for (int e=0;e<16;e++){
    int r = rbase + (e&3) + 8*(e>>2);
    float oo = acc_o[e] / l_s[r];
    AV[ ((size_t)(i0+r)*B_ + b)*(H_*DH_) + h*DH_ + col ] = f2b(oo);
  }
}

// ---------------- LayerNorm ----------------
__global__ __launch_bounds__(256) void ln_kernel(const float* __restrict__ y,
    const float* __restrict__ g, const float* __restrict__ be, float* __restrict__ o)
{
  __shared__ float red[8];
  int row = blockIdx.x, tid = threadIdx.x;
  const float* yr = y + (size_t)row*DM_;
  float v[4];
  for (int e=0;e<4;e++) v[e] = yr[tid + 256*e];
  float s = v[0]+v[1]+v[2]+v[3];
  for (int off=32; off>0; off>>=1) s += __shfl_down(s, off, 64);
  if ((tid&63)==0) red[tid>>6] = s;
  __syncthreads();
  if (tid==0) red[4] = red[0]+red[1]+red[2]+red[3];
  __syncthreads();
  float mu = red[4] * (1.f/DM_);
  __syncthreads();
  float q = 0.f;
  for (int e=0;e<4;e++){ float d = v[e]-mu; q += d*d; }
  for (int off=32; off>0; off>>=1) q += __shfl_down(q, off, 64);
  if ((tid&63)==0) red[tid>>6] = q;
  __syncthreads();
  if (tid==0) red[4] = red[0]+red[1]+red[2]+red[3];
  __syncthreads();
  float rstd = rsqrtf(red[4]*(1.f/DM_) + 1e-5f);
  for (int e=0;e<4;e++){
    int c = tid + 256*e;
    o[(size_t)row*DM_ + c] = g[c]*(v[e]-mu)*rstd + be[c];
  }
}

// ---------------- launch ----------------
extern "C" void kernel_launch(void* const* d_in, const int* in_sizes, int n_in,
                              void* d_out, int out_size, void* d_ws, size_t ws_size,
                              hipStream_t stream)
{
  const float* x    = (const float*)d_in[0];
  const float* mem  = (const float*)d_in[1];
  const float* pos  = (const float*)d_in[2];
  const float* pbu  = (const float*)d_in[3];
  const float* pbv  = (const float*)d_in[4];
  const float* wqkv = (const float*)d_in[5];
  const float* wrel = (const float*)d_in[6];
  const float* wo   = (const float*)d_in[7];
  const float* gam  = (const float*)d_in[8];
  const float* bet  = (const float*)d_in[9];
  float* out = (float*)d_out;

  char* w = (char*)d_ws;
  unsigned short* qkvo  = (unsigned short*)(w + 0);          // 50,331,648
  unsigned short* relo  = (unsigned short*)(w + 50331648);   // 16,777,216
  unsigned short* wo16  = (unsigned short*)(w + 67108864);   //  2,097,152
  unsigned short* QUb   = (unsigned short*)(w + 69206016);   //  8,388,608
  unsigned short* QVb   = (unsigned short*)(w + 77594624);   //  8,388,608
  unsigned short* VT    = (unsigned short*)(w + 85983232);   // 16,777,216
  unsigned short* av16  = (unsigned short*)(w + 102760448);  //  8,388,608
  float*          yf    = (float*)(w + 111149056);           // 16,777,216
  unsigned short* c16   = (unsigned short*)(w + 127926272);  // 16,777,216
  unsigned short* pos16 = (unsigned short*)(w + 144703488);  // 16,777,216
  unsigned short* wq16  = (unsigned short*)(w + 161480704);  //  6,291,456
  unsigned short* wr16  = (unsigned short*)(w + 167772160);  //  2,097,152 -> total 169,869,312

  cast_cat<<<4096, 256, 0, stream>>>(mem, x, c16, 1048576, 524288);
  cast_cat<<<4096, 256, 0, stream>>>(pos, pos, pos16, 1048576, 1048576);
  cast_cat<<<1536, 256, 0, stream>>>(wqkv, wqkv, wq16, 393216, 393216);
  cast_cat<<< 512, 256, 0, stream>>>(wrel, wrel, wr16, 131072, 131072);
  cast_cat<<< 512, 256, 0, stream>>>(wo,   wo,   wo16, 131072, 131072);

  gemm_nt<<<dim3(24,64), 256, 0, stream>>>(c16,   wq16, (void*)qkvo, nullptr, 3072, 1024, 0);
  gemm_nt<<<dim3(8,64),  256, 0, stream>>>(pos16, wr16, (void*)relo, nullptr, 1024, 1024, 0);

  scatter_quv<<<2048, 256, 0, stream>>>(qkvo, pbu, pbv, QUb, QVb);
  scatter_vt<<<dim3(64,32), 256, 0, stream>>>(qkvo, VT);

  flash_attn4<<<dim3(64,16), 256, 0, stream>>>(QUb, QVb, qkvo, VT, relo, av16);

  gemm_nt<<<dim3(8,32), 256, 0, stream>>>(av16, wo16, (void*)yf, x, 1024, 1024, 1);
  ln_kernel<<<4096, 256, 0, stream>>>(yf, gam, bet, out);
}

// Round 4
// 503.943 us; speedup vs baseline: 2.0473x; 1.0369x over previous
//
#include <hip/hip_runtime.h>

#define S_ 1024
#define M_ 1024
#define T_ 2048
#define B_ 4
#define H_ 16
#define DM_ 1024
#define DH_ 64

typedef __attribute__((ext_vector_type(8))) short s16x8;
typedef __attribute__((ext_vector_type(16))) float f32x16;

__device__ __forceinline__ unsigned short f2b(float x){
  unsigned int u = __float_as_uint(x);
  u = (u + 0x7fffu + ((u>>16)&1u)) >> 16;
  return (unsigned short)u;
}
__device__ __forceinline__ float b2f(unsigned short h){
  return __uint_as_float(((unsigned int)h)<<16);
}
__device__ __forceinline__ uint4 pack8(const float* v){
  uint4 o;
  o.x = (unsigned)f2b(v[0]) | ((unsigned)f2b(v[1])<<16);
  o.y = (unsigned)f2b(v[2]) | ((unsigned)f2b(v[3])<<16);
  o.z = (unsigned)f2b(v[4]) | ((unsigned)f2b(v[5])<<16);
  o.w = (unsigned)f2b(v[6]) | ((unsigned)f2b(v[7])<<16);
  return o;
}
__device__ __forceinline__ void glds16(const unsigned short* g, unsigned short* l){
  __builtin_amdgcn_global_load_lds((const __attribute__((address_space(1))) void*)g,
                                   (__attribute__((address_space(3))) void*)l, 16, 0, 0);
}

// raw barriers: BAR_L waits only LDS ops (leaves glds prefetches in flight);
// BAR_VL additionally drains vmcnt.
#define BAR_L()  asm volatile("s_waitcnt lgkmcnt(0)\ns_barrier" ::: "memory")
#define BAR_VL() asm volatile("s_waitcnt vmcnt(0) lgkmcnt(0)\ns_barrier" ::: "memory")

// ---------------- fused cast kernel (5 launches -> 1) ----------------
// unit = 8 floats. segments:
//   [0,        524288): mem  -> c16[u]
//   [524288,  1048576): x    -> c16[u]
//   [1048576, 2097152): pos  -> pos16
//   [2097152, 2490368): wqkv -> wq16
//   [2490368, 2621440): wrel -> wr16
//   [2621440, 2752512): wo   -> wo16
__global__ __launch_bounds__(256) void cast_all(
    const float* __restrict__ mem, const float* __restrict__ x,
    const float* __restrict__ pos, const float* __restrict__ wqkv,
    const float* __restrict__ wrel, const float* __restrict__ wo,
    unsigned short* __restrict__ c16, unsigned short* __restrict__ pos16,
    unsigned short* __restrict__ wq16, unsigned short* __restrict__ wr16,
    unsigned short* __restrict__ wo16)
{
  int u = blockIdx.x*256 + threadIdx.x;
  const float* s; unsigned short* d;
  if (u < 1048576)      { s = (u < 524288) ? mem + (size_t)u*8 : x + (size_t)(u-524288)*8;
                          d = c16 + (size_t)u*8; }
  else if (u < 2097152) { int v = u - 1048576; s = pos  + (size_t)v*8; d = pos16 + (size_t)v*8; }
  else if (u < 2490368) { int v = u - 2097152; s = wqkv + (size_t)v*8; d = wq16  + (size_t)v*8; }
  else if (u < 2621440) { int v = u - 2490368; s = wrel + (size_t)v*8; d = wr16  + (size_t)v*8; }
  else                  { int v = u - 2621440; s = wo   + (size_t)v*8; d = wo16  + (size_t)v*8; }
  float4 x0 = *(const float4*)s;
  float4 x1 = *(const float4*)(s+4);
  float f[8] = {x0.x,x0.y,x0.z,x0.w,x1.x,x1.y,x1.z,x1.w};
  *(uint4*)d = pack8(f);
}

// ---------------- GEMM: C[M][N] = A[M][K] @ B[N][K]^T  (bf16 in, NT) ----------------
__global__ __launch_bounds__(256) void gemm_nt(const unsigned short* __restrict__ A,
    const unsigned short* __restrict__ Bw, void* __restrict__ Cout,
    const float* __restrict__ res, int Ntot, int K, int mode)
{
  __shared__ __align__(16) unsigned short a_s[128*64];
  __shared__ __align__(16) unsigned short b_s[128*64];
  const int tid = threadIdx.x;
  const int lane = tid & 63, wave = tid >> 6;
  const int wr = wave >> 1, wc = wave & 1;
  const long m0 = (long)blockIdx.y * 128, n0 = (long)blockIdx.x * 128;
  f32x16 acc[2][2];
  for (int qa=0;qa<2;qa++) for(int qb=0;qb<2;qb++) for (int e=0;e<16;e++) acc[qa][qb][e]=0.f;
  int srow[4], scol[4];
  for (int c = 0; c < 4; c++) {
    int ch = c*256 + tid;
    srow[c] = ch >> 3;
    scol[c] = (((ch & 7) ^ (srow[c] & 7))) * 8;
  }
  for (int k0 = 0; k0 < K; k0 += 64) {
    for (int c = 0; c < 4; c++) {
      int ch = c*256 + tid;
      glds16(&A[(size_t)(m0+srow[c])*K + k0 + scol[c]], &a_s[ch*8]);
      glds16(&Bw[(size_t)(n0+srow[c])*K + k0 + scol[c]], &b_s[ch*8]);
    }
    __syncthreads();
    for (int ks = 0; ks < 4; ks++) {
      const int kb = ks*2 + (lane>>5);
      s16x8 af[2], bf[2];
      for (int q = 0; q < 2; q++) {
        int ra = wr*64 + q*32 + (lane&31);
        int rb = wc*64 + q*32 + (lane&31);
        af[q] = *(const s16x8*)&a_s[ra*64 + ((kb ^ (ra&7))<<3)];
        bf[q] = *(const s16x8*)&b_s[rb*64 + ((kb ^ (rb&7))<<3)];
      }
      for (int qr=0;qr<2;qr++)
        for (int qc2=0;qc2<2;qc2++)
          acc[qr][qc2] = __builtin_amdgcn_mfma_f32_32x32x16_bf16(af[qr], bf[qc2], acc[qr][qc2], 0,0,0);
    }
    __syncthreads();
  }
  for (int qr=0;qr<2;qr++)
    for (int qc2=0;qc2<2;qc2++)
      for (int e=0;e<16;e++){
        long row = m0 + wr*64 + qr*32 + (e&3) + 8*(e>>2) + 4*(lane>>5);
        long col = n0 + wc*64 + qc2*32 + (lane&31);
        size_t o = (size_t)row*Ntot + col;
        if (mode == 0) ((unsigned short*)Cout)[o] = f2b(acc[qr][qc2][e]);
        else           ((float*)Cout)[o] = acc[qr][qc2][e] + res[o];
      }
}

// ---------------- scatter: q + biases, per-head layout ----------------
__global__ __launch_bounds__(256) void scatter_quv(const unsigned short* __restrict__ qkvo,
   const float* __restrict__ u, const float* __restrict__ v,
   unsigned short* __restrict__ QU, unsigned short* __restrict__ QV)
{
  int gid = blockIdx.x*256 + threadIdx.x;   // B*H*S*8 = 524288
  int d0 = (gid & 7) * 8;
  int i  = (gid >> 3) & (S_-1);
  int bh = gid >> 13;
  int b = bh >> 4, h = bh & 15;
  size_t src = (size_t)((M_+i)*B_ + b)*3072 + h*64 + d0;
  uint4 q8 = *(const uint4*)&qkvo[src];
  float f[8];
  f[0]=b2f(q8.x&0xffff); f[1]=b2f(q8.x>>16); f[2]=b2f(q8.y&0xffff); f[3]=b2f(q8.y>>16);
  f[4]=b2f(q8.z&0xffff); f[5]=b2f(q8.z>>16); f[6]=b2f(q8.w&0xffff); f[7]=b2f(q8.w>>16);
  float fu[8], fv[8];
  for (int e=0;e<8;e++){ fu[e] = f[e] + u[h*64+d0+e]; fv[e] = f[e] + v[h*64+d0+e]; }
  size_t dst = ((size_t)bh*S_ + i)*64 + d0;
  *(uint4*)&QU[dst] = pack8(fu);
  *(uint4*)&QV[dst] = pack8(fv);
}

// ---------------- scatter_vt: VT[bh][d][t] = V[t][b][h][d] (LDS transpose) ----------------
__global__ __launch_bounds__(256) void scatter_vt(const unsigned short* __restrict__ qkvo,
    unsigned short* __restrict__ VT)
{
  __shared__ __align__(16) unsigned short v_s[64*72];
  const int tid = threadIdx.x;
  const int bh = blockIdx.x, b = bh>>4, h = bh&15;
  const int t0 = blockIdx.y*64;
  const unsigned short* Vg = qkvo + (size_t)b*3072 + 2048 + h*64;
  for (int c=0;c<2;c++){
    int ch = c*256 + tid;
    int r = ch>>3, off = (ch&7)*8;
    *(uint4*)&v_s[r*72+off] = *(const uint4*)&Vg[(size_t)(t0+r)*12288 + off];
  }
  __syncthreads();
  for (int c=0;c<2;c++){
    int ch = c*256 + tid;
    int d = ch>>3, toff = (ch&7)*8;
    unsigned short vals[8];
    for (int e=0;e<8;e++) vals[e] = v_s[(toff+e)*72 + d];
    uint4 pk;
    pk.x = (unsigned)vals[0] | ((unsigned)vals[1]<<16);
    pk.y = (unsigned)vals[2] | ((unsigned)vals[3]<<16);
    pk.z = (unsigned)vals[4] | ((unsigned)vals[5]<<16);
    pk.w = (unsigned)vals[6] | ((unsigned)vals[7]<<16);
    *(uint4*)&VT[((size_t)bh*64 + d)*T_ + t0 + toff] = pk;
  }
}

// ---------------- fused attention v8 ----------------
// v8 = v7 minus the G LDS round-trip:
//   * each wave computes ITS OWN two band quads at cbase=(qc-qr+1)*32, so the
//     BD gather bd[r][col] = G[r][col-r+63] only needs the wave's own 64-col
//     window -> G stays in registers.
//   * gather = intra-wave lane rotate: source lane ((L&31)-rm+31)&31 + 32*hi,
//     same register e, quad selected by (L&31)>rm. Two ds_bpermute + cndmask
//     per element, executed UNCONDITIONALLY (predicated writes only).
//   * removes 32 ds_write_u16 + 16 ds_read_u16 + 1 barrier per iter
//     (cls0/2: 3 barriers; cls1: 4 barriers vs 7 in v7).
//   * rg_s holds only R -> R(next) prefetch moves up to B2.
// LDS: qu 9216 + qv 9360 + K 8192 + VT 2x8192 + R 16384 + P 9216 + l 256
//   = 69008 B -> 2 blocks/CU. __launch_bounds__(256,2) (NO (256,3): rounds 1-2
//   showed the ~170-reg cap spills with this accumulator footprint).
__global__ __launch_bounds__(256,2) void flash_attn4(
    const unsigned short* __restrict__ QU, const unsigned short* __restrict__ QV,
    const unsigned short* __restrict__ qkvo, const unsigned short* __restrict__ VT,
    const unsigned short* __restrict__ relo, unsigned short* __restrict__ AV)
{
  __shared__ __align__(16) unsigned short qu_s[64*72];
  __shared__ __align__(16) unsigned short qv_s[65*72];
  __shared__ __align__(16) unsigned short k_s [64*64];      // XOR-64 layout
  __shared__ __align__(16) unsigned short vt_s[2][64*64];   // XOR-64, double-buffered
  __shared__ __align__(16) unsigned short rg_s[128*64];     // R window (XOR slots)
  __shared__ __align__(16) unsigned short p_s [64*72];
  __shared__ float l_s[64];

  const int tid = threadIdx.x, lane = tid&63, wave = tid>>6;
  const int bh = blockIdx.x, b = bh>>4, h = bh&15;
  const int i0 = blockIdx.y*64;
  const int qr = wave>>1, qc = wave&1;
  const int hi = lane>>5, ll = lane&31;
  const unsigned short* QUb = QU + (size_t)bh*S_*DH_;
  const unsigned short* QVb = QV + (size_t)bh*S_*DH_;
  const unsigned short* Kg  = qkvo + (size_t)b*3072 + 1024 + h*64;   // + t*12288
  const unsigned short* VTb = VT + (size_t)bh*64*T_;
  const unsigned short* Rg  = relo + (size_t)b*1024 + h*64;          // + t*4096

  // per-thread staging geometry (2-chunk tiles: K, VT)
  const int s0r = tid>>3,        s0c = (((tid&7)       ^ (s0r&7)))*8;
  const int s1r = (256+tid)>>3,  s1c = ((((256+tid)&7) ^ (s1r&7)))*8;

  int vb = 0;

  // ---- prologue: issue DMA for tile 0, plain-stage QU/QV ----
  glds16(&Kg [(size_t)(0+s0r)*12288 + s0c], &k_s[(size_t)tid*8]);
  glds16(&Kg [(size_t)(0+s1r)*12288 + s1c], &k_s[(size_t)(256+tid)*8]);
  glds16(&VTb[(size_t)s0r*T_ + 0 + s0c],    &vt_s[0][(size_t)tid*8]);
  glds16(&VTb[(size_t)s1r*T_ + 0 + s1c],    &vt_s[0][(size_t)(256+tid)*8]);
  {
    const int wb0 = 0 - i0 + 960;    // j0=0 is always cls 0
    for (int c=0;c<4;c++){
      int ch = c*256+tid; int rr = ch>>3, off = ch&7;
      int t = wb0 + rr; t = t < 0 ? 0 : (t > T_-1 ? T_-1 : t);
      int sc = ((off ^ (rr&7)))*8;
      glds16(&Rg[(size_t)t*4096 + sc], &rg_s[(size_t)ch*8]);
    }
  }
  for (int c=0;c<2;c++){
    int ch = c*256+tid; int row = ch>>3, off=(ch&7)*8;
    *(uint4*)&qu_s[row*72+off] = *(const uint4*)&QUb[(size_t)(i0+row)*64 + off];
    *(uint4*)&qv_s[row*72+off] = *(const uint4*)&QVb[(size_t)(i0+row)*64 + off];
  }
  if (tid < 8) {
    int rr = i0 + 64; if (rr > S_-1) rr = S_-1;
    *(uint4*)&qv_s[64*72 + tid*8] = *(const uint4*)&QVb[(size_t)rr*64 + tid*8];
  }

  f32x16 acc_o;
  for (int e=0;e<16;e++) acc_o[e]=0.f;
  float lreg = 0.f;

  const int col = qc*32 + ll;
  const int cbase = (qc - qr + 1) * 32;   // wave's band-quad column base

  for (int j0 = 0; j0 < T_; j0 += 64) {
    const int jdmax = j0 + 63 - i0;
    const int jdmin = j0 - 63 - i0;
    const int cls = (jdmax <= 1024) ? 0 : ((jdmin >= 1026) ? 2 : 1);
    const int ashift = (cls == 2) ? 1 : 0;
    const int jn = j0 + 64;

    BAR_VL();                  // B1: all staged data (DMA + plain) visible

    // prefetch VT(next) into the other buffer (consumed at next iter's PV)
    if (jn < T_) {
      glds16(&VTb[(size_t)s0r*T_ + jn + s0c], &vt_s[vb^1][(size_t)tid*8]);
      glds16(&VTb[(size_t)s1r*T_ + jn + s1c], &vt_s[vb^1][(size_t)(256+tid)*8]);
    }

    // band GEMM: the wave's OWN 2 quads at cbase (kept in registers)
    f32x16 gacc0, gacc1;
    for (int e=0;e<16;e++){ gacc0[e]=0.f; gacc1[e]=0.f; }
    __builtin_amdgcn_s_setprio(1);
    for (int ks=0; ks<4; ks++){
      int koff = ks*16 + hi*8, kb = ks*2 + hi;
      int ar = qr*32 + ll + ashift;
      s16x8 a  = *(const s16x8*)&qv_s[ar*72 + koff];
      {
        int br = cbase + ll;
        s16x8 bb = *(const s16x8*)&rg_s[br*64 + ((kb ^ (br&7))<<3)];
        gacc0 = __builtin_amdgcn_mfma_f32_32x32x16_bf16(a, bb, gacc0, 0,0,0);
      }
      {
        int br = cbase + 32 + ll;
        s16x8 bb = *(const s16x8*)&rg_s[br*64 + ((kb ^ (br&7))<<3)];
        gacc1 = __builtin_amdgcn_mfma_f32_32x32x16_bf16(a, bb, gacc1, 0,0,0);
      }
    }
    // AC quad
    f32x16 acc;
    for (int e=0;e<16;e++) acc[e]=0.f;
    for (int ks=0; ks<4; ks++){
      int koff = ks*16 + hi*8, kb = ks*2 + hi;
      int rbk = qc*32 + ll;
      s16x8 a  = *(const s16x8*)&qu_s[(qr*32+ll)*72 + koff];
      s16x8 bq = *(const s16x8*)&k_s[rbk*64 + ((kb ^ (rbk&7))<<3)];
      acc = __builtin_amdgcn_mfma_f32_32x32x16_bf16(a, bq, acc, 0,0,0);
    }
    __builtin_amdgcn_s_setprio(0);
    BAR_L();                   // B2: rg_s(R) and k_s(K) consumed by all waves

    // prefetch K(next); R(next) too unless cls1 needs the wrap window first
    if (jn < T_) {
      glds16(&Kg[(size_t)(jn+s0r)*12288 + s0c], &k_s[(size_t)tid*8]);
      glds16(&Kg[(size_t)(jn+s1r)*12288 + s1c], &k_s[(size_t)(256+tid)*8]);
      if (cls != 1) {
        const int jdmaxn = jn + 63 - i0;
        const int jdminn = jn - 63 - i0;
        const int clsn = (jdmaxn <= 1024) ? 0 : ((jdminn >= 1026) ? 2 : 1);
        const int wbn = (clsn == 2) ? (jn - i0 - 1089) : (jn - i0 + 960);
        for (int c=0;c<4;c++){
          int ch = c*256+tid; int rr = ch>>3, off = ch&7;
          int t = wbn + rr; t = t < 0 ? 0 : (t > T_-1 ? T_-1 : t);
          int sc = ((off ^ (rr&7)))*8;
          glds16(&Rg[(size_t)t*4096 + sc], &rg_s[(size_t)ch*8]);
        }
      }
    }

    // in-register gather + exp -> P  (phase A: all of cls0/2, jd<=1025 of cls1)
    for (int e=0;e<16;e++){
      int rm = 4*hi + (e&3) + 8*(e>>2);     // r - qr*32
      int r  = qr*32 + rm;
      int jd = j0 + col - (i0 + r);
      int li = ((((ll - rm + 31) & 31) | (hi<<5)) << 2);
      float g0 = __uint_as_float((unsigned)__builtin_amdgcn_ds_bpermute(li, (int)__float_as_uint(gacc0[e])));
      float g1 = __uint_as_float((unsigned)__builtin_amdgcn_ds_bpermute(li, (int)__float_as_uint(gacc1[e])));
      float bd = (ll > rm) ? g1 : g0;
      if (jd == 1025) bd = 0.f;
      float p = __expf((acc[e] + bd) * 0.125f);
      if (!(cls == 1 && jd >= 1026)) p_s[r*72 + col] = f2b(p);
    }

    if (cls == 1) {
      // stage wrap R window (rg_s free since B2; cls1 skipped R-next above)
      const int wb2 = j0 - i0 - 1089;
      for (int c=0;c<4;c++){
        int ch = c*256+tid; int rr = ch>>3, off = ch&7;
        int t = wb2 + rr; t = t < 0 ? 0 : (t > T_-1 ? T_-1 : t);
        int sc = ((off ^ (rr&7)))*8;
        glds16(&Rg[(size_t)t*4096 + sc], &rg_s[(size_t)ch*8]);
      }
      BAR_VL();                // C2: wrap R visible (drains other prefetches too)
      f32x16 g2a, g2b;
      for (int e=0;e<16;e++){ g2a[e]=0.f; g2b[e]=0.f; }
      __builtin_amdgcn_s_setprio(1);
      for (int ks=0; ks<4; ks++){
        int koff = ks*16 + hi*8, kb = ks*2 + hi;
        int ar = qr*32 + ll + 1;           // wrap band uses QV[i+1]
        s16x8 a  = *(const s16x8*)&qv_s[ar*72 + koff];
        {
          int br = cbase + ll;
          s16x8 bb = *(const s16x8*)&rg_s[br*64 + ((kb ^ (br&7))<<3)];
          g2a = __builtin_amdgcn_mfma_f32_32x32x16_bf16(a, bb, g2a, 0,0,0);
        }
        {
          int br = cbase + 32 + ll;
          s16x8 bb = *(const s16x8*)&rg_s[br*64 + ((kb ^ (br&7))<<3)];
          g2b = __builtin_amdgcn_mfma_f32_32x32x16_bf16(a, bb, g2b, 0,0,0);
        }
      }
      __builtin_amdgcn_s_setprio(0);
      for (int e=0;e<16;e++){
        int rm = 4*hi + (e&3) + 8*(e>>2);
        int r  = qr*32 + rm;
        int jd = j0 + col - (i0 + r);
        int li = ((((ll - rm + 31) & 31) | (hi<<5)) << 2);
        float g0 = __uint_as_float((unsigned)__builtin_amdgcn_ds_bpermute(li, (int)__float_as_uint(g2a[e])));
        float g1 = __uint_as_float((unsigned)__builtin_amdgcn_ds_bpermute(li, (int)__float_as_uint(g2b[e])));
        float bd = (ll > rm) ? g1 : g0;
        float p = __expf((acc[e] + bd) * 0.125f);
        if (jd >= 1026) p_s[r*72 + col] = f2b(p);
      }
      BAR_L();                 // C3: P visible; wrap-R band reads drained
      // R(next) prefetch (deferred past the wrap window use)
      if (jn < T_) {
        const int jdmaxn = jn + 63 - i0;
        const int jdminn = jn - 63 - i0;
        const int clsn = (jdmaxn <= 1024) ? 0 : ((jdminn >= 1026) ? 2 : 1);
        const int wbn = (clsn == 2) ? (jn - i0 - 1089) : (jn - i0 + 960);
        for (int c=0;c<4;c++){
          int ch = c*256+tid; int rr = ch>>3, off = ch&7;
          int t = wbn + rr; t = t < 0 ? 0 : (t > T_-1 ? T_-1 : t);
          int sc = ((off ^ (rr&7)))*8;
          glds16(&Rg[(size_t)t*4096 + sc], &rg_s[(size_t)ch*8]);
        }
      }
    } else {
      BAR_L();                 // B3: P visible
    }

    // rowsum (4 threads per row) from p_s
    {
      int rr = tid>>2, cb = (tid&3)*16;
      uint4 x0 = *(const uint4*)&p_s[rr*72+cb];
      uint4 x1 = *(const uint4*)&p_s[rr*72+cb+8];
      unsigned vs[8] = {x0.x,x0.y,x0.z,x0.w,x1.x,x1.y,x1.z,x1.w};
      float s = 0.f;
      for (int e=0;e<8;e++) s += b2f((unsigned short)(vs[e]&0xffff)) + b2f((unsigned short)(vs[e]>>16));
      s += __shfl_xor(s, 1, 64);
      s += __shfl_xor(s, 2, 64);
      if ((tid&3)==0) lreg += s;
    }
    // PV quad (reads p_s, vt_s[vb] in XOR-64 layout)
    __builtin_amdgcn_s_setprio(1);
    for (int ks=0; ks<4; ks++){
      int koff = ks*16 + hi*8, kb = ks*2 + hi;
      int rbv = qc*32 + ll;
      s16x8 a  = *(const s16x8*)&p_s[(qr*32+ll)*72 + koff];
      s16x8 bv = *(const s16x8*)&vt_s[vb][rbv*64 + ((kb ^ (rbv&7))<<3)];
      acc_o = __builtin_amdgcn_mfma_f32_32x32x16_bf16(a, bv, acc_o, 0,0,0);
    }
    __builtin_amdgcn_s_setprio(0);
    vb ^= 1;
    // no trailing barrier: loop-top BAR_VL() orders everything
  }

  if ((tid&3)==0) l_s[tid>>2] = lreg;
  BAR_L();
  for (int e=0;e<16;e++){
    int r = qr*32 + 4*hi + (e&3) + 8*(e>>2);
    float oo = acc_o[e] / l_s[r];
    AV[ ((size_t)(i0+r)*B_ + b)*(H_*DH_) + h*DH_ + col ] = f2b(oo);
  }
}

// ---------------- LayerNorm ----------------
__global__ __launch_bounds__(256) void ln_kernel(const float* __restrict__ y,
    const float* __restrict__ g, const float* __restrict__ be, float* __restrict__ o)
{
  __shared__ float red[8];
  int row = blockIdx.x, tid = threadIdx.x;
  const float* yr = y + (size_t)row*DM_;
  float v[4];
  for (int e=0;e<4;e++) v[e] = yr[tid + 256*e];
  float s = v[0]+v[1]+v[2]+v[3];
  for (int off=32; off>0; off>>=1) s += __shfl_down(s, off, 64);
  if ((tid&63)==0) red[tid>>6] = s;
  __syncthreads();
  if (tid==0) red[4] = red[0]+red[1]+red[2]+red[3];
  __syncthreads();
  float mu = red[4] * (1.f/DM_);
  __syncthreads();
  float q = 0.f;
  for (int e=0;e<4;e++){ float d = v[e]-mu; q += d*d; }
  for (int off=32; off>0; off>>=1) q += __shfl_down(q, off, 64);
  if ((tid&63)==0) red[tid>>6] = q;
  __syncthreads();
  if (tid==0) red[4] = red[0]+red[1]+red[2]+red[3];
  __syncthreads();
  float rstd = rsqrtf(red[4]*(1.f/DM_) + 1e-5f);
  for (int e=0;e<4;e++){
    int c = tid + 256*e;
    o[(size_t)row*DM_ + c] = g[c]*(v[e]-mu)*rstd + be[c];
  }
}

// ---------------- launch ----------------
extern "C" void kernel_launch(void* const* d_in, const int* in_sizes, int n_in,
                              void* d_out, int out_size, void* d_ws, size_t ws_size,
                              hipStream_t stream)
{
  const float* x    = (const float*)d_in[0];
  const float* mem  = (const float*)d_in[1];
  const float* pos  = (const float*)d_in[2];
  const float* pbu  = (const float*)d_in[3];
  const float* pbv  = (const float*)d_in[4];
  const float* wqkv = (const float*)d_in[5];
  const float* wrel = (const float*)d_in[6];
  const float* wo   = (const float*)d_in[7];
  const float* gam  = (const float*)d_in[8];
  const float* bet  = (const float*)d_in[9];
  float* out = (float*)d_out;

  char* w = (char*)d_ws;
  unsigned short* qkvo  = (unsigned short*)(w + 0);          // 50,331,648
  unsigned short* relo  = (unsigned short*)(w + 50331648);   // 16,777,216
  unsigned short* wo16  = (unsigned short*)(w + 67108864);   //  2,097,152
  unsigned short* QUb   = (unsigned short*)(w + 69206016);   //  8,388,608
  unsigned short* QVb   = (unsigned short*)(w + 77594624);   //  8,388,608
  unsigned short* VT    = (unsigned short*)(w + 85983232);   // 16,777,216
  unsigned short* av16  = (unsigned short*)(w + 102760448);  //  8,388,608
  float*          yf    = (float*)(w + 111149056);           // 16,777,216
  unsigned short* c16   = (unsigned short*)(w + 127926272);  // 16,777,216
  unsigned short* pos16 = (unsigned short*)(w + 144703488);  // 16,777,216
  unsigned short* wq16  = (unsigned short*)(w + 161480704);  //  6,291,456
  unsigned short* wr16  = (unsigned short*)(w + 167772160);  //  2,097,152 -> total 169,869,312

  cast_all<<<10752, 256, 0, stream>>>(mem, x, pos, wqkv, wrel, wo,
                                      c16, pos16, wq16, wr16, wo16);

  gemm_nt<<<dim3(24,64), 256, 0, stream>>>(c16,   wq16, (void*)qkvo, nullptr, 3072, 1024, 0);
  gemm_nt<<<dim3(8,64),  256, 0, stream>>>(pos16, wr16, (void*)relo, nullptr, 1024, 1024, 0);

  scatter_quv<<<2048, 256, 0, stream>>>(qkvo, pbu, pbv, QUb, QVb);
  scatter_vt<<<dim3(64,32), 256, 0, stream>>>(qkvo, VT);

  flash_attn4<<<dim3(64,16), 256, 0, stream>>>(QUb, QVb, qkvo, VT, relo, av16);

  gemm_nt<<<dim3(8,32), 256, 0, stream>>>(av16, wo16, (void*)yf, x, 1024, 1024, 1);
  ln_kernel<<<4096, 256, 0, stream>>>(yf, gam, bet, out);
}